// Round 10
// baseline (531.818 us; speedup 1.0000x reference)
//
#include <hip/hip_runtime.h>

typedef unsigned int  uint32;
typedef float  f32x4   __attribute__((ext_vector_type(4)));
typedef __bf16 bf16x8  __attribute__((ext_vector_type(8)));
typedef short  s16x4   __attribute__((ext_vector_type(4)));

__device__ __forceinline__ float bf2f(unsigned int u) {
  return __builtin_bit_cast(float, u << 16);
}
__device__ __forceinline__ unsigned short f2bf(float f) {
  uint32 u = __builtin_bit_cast(uint32, f);
  u += 0x7fffu + ((u >> 16) & 1u);          // RNE
  return (unsigned short)(u >> 16);
}

__device__ __forceinline__ void gload_lds16(const void* g, void* l) {
  __builtin_amdgcn_global_load_lds(
      (const __attribute__((address_space(1))) void*)g,
      (__attribute__((address_space(3))) void*)l, 16, 0, 0);
}

// ---------------- fp32 -> bf16 cast (8 elems/thread) ----------------
__global__ __launch_bounds__(256) void cast_kernel(
    const float* __restrict__ x, unsigned short* __restrict__ y, int n8) {
  int i = blockIdx.x * 256 + threadIdx.x;
  if (i >= n8) return;
  const float4* xp = (const float4*)x;
  float4 a = xp[2 * i], b = xp[2 * i + 1];
  uint4 o;
  o.x = (uint32)f2bf(a.x) | ((uint32)f2bf(a.y) << 16);
  o.y = (uint32)f2bf(a.z) | ((uint32)f2bf(a.w) << 16);
  o.z = (uint32)f2bf(b.x) | ((uint32)f2bf(b.y) << 16);
  o.w = (uint32)f2bf(b.z) | ((uint32)f2bf(b.w) << 16);
  ((uint4*)y)[i] = o;
}

// ---------------- concat two 1024-float bias vectors ----------------
__global__ __launch_bounds__(256) void cat2_kernel(
    const float* __restrict__ a, const float* __restrict__ b,
    float* __restrict__ o) {
  int i = blockIdx.x * 256 + threadIdx.x;
  o[i] = (i < 1024) ? a[i] : b[i - 1024];
}

// ------- bf16 GEMM: C[M,N] = A[M,K] * W[N,K]^T + bias -------
// 256x256 tile, BK=64, 8 waves (2M x 4N), TWO LDS buffers (2 x 64KB),
// m201-style 4-phase K-tile schedule: per phase {ds_read quadrant frags ->
// barrier -> lgkmcnt(0) -> setprio+16 MFMA -> barrier}; tile t+1 staged at
// iter top into dbuf^1; counted vmcnt(8) + publish barrier per tile.
// st_16x32-style XOR swizzle (row 128B: chunk16 ^= row&7).
// EPI=0: bf16 out.  EPI=1: fp32 out = acc + bias + resid.
template <int EPI>
__global__ __launch_bounds__(512, 2) void gemm256(
    const unsigned short* __restrict__ A, const unsigned short* __restrict__ W,
    const float* __restrict__ bias, const float* __restrict__ resid,
    unsigned short* __restrict__ Ob, float* __restrict__ Of,
    int M, int N, int K) {
  __shared__ char smem[131072];  // 2 bufs x (A 32KB | B 32KB)
  const int tid  = threadIdx.x;
  const int lane = tid & 63;
  const int wave = tid >> 6;      // 0..7
  const int wr   = wave >> 2;     // 0..1 : m half (128 rows)
  const int wc   = wave & 3;      // 0..3 : n quarter (64 cols)

  // XCD chunk (bijective, nwg%8==0): n-fastest within chunk for A L2-reuse.
  const int nwg = gridDim.x;
  const int xcd = blockIdx.x & 7;
  const int r   = blockIdx.x >> 3;          // 0 .. nwg/8-1
  const int NT  = N >> 8;                   // n-tiles
  const int m0  = (xcd * ((nwg >> 3) / NT) + r / NT) << 8;
  const int n0  = (r % NT) << 8;

  f32x4 acc[8][4];
#pragma unroll
  for (int m = 0; m < 8; ++m)
#pragma unroll
    for (int n = 0; n < 4; ++n) acc[m][n] = (f32x4)0.0f;

  // ---- staging geometry (inverse-swizzled global source, linear LDS dest).
  const int pr8 = lane >> 3;
  const int cl  = (lane & 7) ^ pr8;
  const unsigned short* As = A + (size_t)(m0 + wave * 8 + pr8) * K + cl * 8;
  const unsigned short* Bs = W + (size_t)(n0 + wave * 8 + pr8) * K + cl * 8;
  const int dst = wave * 1024 + lane * 16;

#define STAGE(d, kt)                                                          \
  {                                                                           \
    char* sb = smem + (d) * 65536;                                            \
    const int ko = (kt) * 64;                                                 \
    _Pragma("unroll") for (int j = 0; j < 4; ++j)                             \
        gload_lds16(As + (size_t)(j * 64) * K + ko, sb + j * 8192 + dst);     \
    _Pragma("unroll") for (int j = 0; j < 4; ++j)                             \
        gload_lds16(Bs + (size_t)(j * 64) * K + ko,                           \
                    sb + 32768 + j * 8192 + dst);                             \
  }

  // ---- fragment read offsets (swizzled): row r, k-chunk c (= ks*4+kg):
  // byte = r*128 + (c ^ (r&7))*16.
  const int fr = lane & 15, kg = lane >> 4;
  int cA[2];
#pragma unroll
  for (int ks = 0; ks < 2; ++ks)
    cA[ks] = fr * 128 + (((ks * 4 + kg) ^ (fr & 7)) * 16);
  const int abase = wr * 16384;           // + m*2048 + cA[ks]
  const int bbase = 32768 + wc * 8192;    // + n*2048 + cA[ks]

#define PH_A4(base_, av_, mlo, ks)                                            \
  _Pragma("unroll") for (int m = 0; m < 4; ++m)                               \
      av_[m] = *(const bf16x8*)((base_) + abase + ((mlo) + m) * 2048 +        \
                                cA[ks]);
#define PH_B4(base_, bv_, ks)                                                 \
  _Pragma("unroll") for (int n = 0; n < 4; ++n)                               \
      bv_[n] = *(const bf16x8*)((base_) + bbase + n * 2048 + cA[ks]);
#define PH_MFMA(av_, bv_, mlo)                                                \
  __builtin_amdgcn_s_setprio(1);                                              \
  _Pragma("unroll") for (int m = 0; m < 4; ++m)                               \
      _Pragma("unroll") for (int n = 0; n < 4; ++n)                           \
          acc[(mlo) + m][n] = __builtin_amdgcn_mfma_f32_16x16x32_bf16(        \
              av_[m], bv_[n], acc[(mlo) + m][n], 0, 0, 0);                    \
  __builtin_amdgcn_s_setprio(0);

  const int nt = K >> 6;  // 64-wide K-tiles
  STAGE(0, 0);

  for (int t = 0; t < nt; ++t) {
    // ---- iter top: stage t+1 into dbuf^1 (WAR-safe: P4's lgkm+barrier of
    // iter t-1 precede this), then publish tile t: queue=[t(8), t+1(8)],
    // drain to 8 -> tile t landed; issue-to-wait lead = one full iter.
    if (t + 1 < nt) {
      STAGE((t + 1) & 1, t + 1);
      asm volatile("s_waitcnt vmcnt(8)" ::: "memory");
    } else {
      asm volatile("s_waitcnt vmcnt(0)" ::: "memory");
    }
    __builtin_amdgcn_s_barrier();          // publish tile t to all waves

    const char* base = smem + (t & 1) * 65536;
    bf16x8 a0[4], a1[4], b0[4], b1[4];

    // ---- P1: quadrant (m0-3, ks0); reads A4+B4
    PH_A4(base, a0, 0, 0);
    PH_B4(base, b0, 0);
    __builtin_amdgcn_s_barrier();
    asm volatile("s_waitcnt lgkmcnt(0)" ::: "memory");
    PH_MFMA(a0, b0, 0);
    __builtin_amdgcn_s_barrier();

    // ---- P2: quadrant (m4-7, ks0); reads A4, reuse b0
    PH_A4(base, a1, 4, 0);
    __builtin_amdgcn_s_barrier();
    asm volatile("s_waitcnt lgkmcnt(0)" ::: "memory");
    PH_MFMA(a1, b0, 4);
    __builtin_amdgcn_s_barrier();

    // ---- P3: quadrant (m0-3, ks1); reads A4+B4
    PH_A4(base, a0, 0, 1);
    PH_B4(base, b1, 1);
    __builtin_amdgcn_s_barrier();
    asm volatile("s_waitcnt lgkmcnt(0)" ::: "memory");
    PH_MFMA(a0, b1, 0);
    __builtin_amdgcn_s_barrier();

    // ---- P4: quadrant (m4-7, ks1); reads A4, reuse b1
    PH_A4(base, a1, 4, 1);
    __builtin_amdgcn_s_barrier();
    asm volatile("s_waitcnt lgkmcnt(0)" ::: "memory");
    PH_MFMA(a1, b1, 4);
    __builtin_amdgcn_s_barrier();          // releases dbuf cur for overwrite
  }

  // ---- epilogue: C/D map col = lane&15, row = (lane>>4)*4 + i.
  // Row-major store order so each row's 4 chunks issue back-to-back.
  const int r4 = (lane >> 4) * 4;
  float bvv[4];
#pragma unroll
  for (int n = 0; n < 4; ++n) bvv[n] = bias[n0 + wc * 64 + n * 16 + fr];
#pragma unroll
  for (int m = 0; m < 8; ++m) {
    const int rowb = m0 + wr * 128 + m * 16 + r4;
#pragma unroll
    for (int i = 0; i < 4; ++i) {
      const size_t rb = (size_t)(rowb + i) * N;
#pragma unroll
      for (int n = 0; n < 4; ++n) {
        const size_t idx = rb + (n0 + wc * 64 + n * 16 + fr);
        float v = acc[m][n][i] + bvv[n];
        if constexpr (EPI == 0) {
          Ob[idx] = f2bf(v);
        } else {
          Of[idx] = v + resid[idx];
        }
      }
    }
  }
#undef STAGE
#undef PH_A4
#undef PH_B4
#undef PH_MFMA
}

// ---------------- head-wise attention, MFMA, one wave per row b ----------
// Q: [B,1024].  K,V packed in KV [B,2048]: K at +0, V at +1024.
// Out: [B,1024] with idx = d*16 + h.
__global__ __launch_bounds__(256) void attn_kernel(
    const unsigned short* __restrict__ Q, const unsigned short* __restrict__ KV,
    unsigned short* __restrict__ O) {
  const int tid  = threadIdx.x;
  const int lane = tid & 63;
  const int wave = tid >> 6;
  const int b    = blockIdx.x * 4 + wave;
  const size_t qb  = (size_t)b * 1024;
  const size_t kvb = (size_t)b * 2048;
  const int fr = lane & 15, kg = lane >> 4;

  // ---- QK^T (transposed): A = K rows (g), B = Q rows (h), K-dim = d (64).
  const bf16x8 kf0 = *(const bf16x8*)(KV + kvb + fr * 64 + kg * 8);
  const bf16x8 kf1 = *(const bf16x8*)(KV + kvb + fr * 64 + 32 + kg * 8);
  const bf16x8 qf0 = *(const bf16x8*)(Q + qb + fr * 64 + kg * 8);
  const bf16x8 qf1 = *(const bf16x8*)(Q + qb + fr * 64 + 32 + kg * 8);

  // ---- V B-fragments: lane (fr=d_local, kg) holds V[kg*4+j][c*16+fr].
  s16x4 vb[4];
#pragma unroll
  for (int c = 0; c < 4; ++c) {
    const unsigned short* vp = KV + kvb + 1024 + c * 16 + fr + kg * 4 * 64;
    s16x4 t;
    t[0] = (short)vp[0];
    t[1] = (short)vp[64];
    t[2] = (short)vp[128];
    t[3] = (short)vp[192];
    vb[c] = t;
  }

  f32x4 es = (f32x4)0.0f;
  es = __builtin_amdgcn_mfma_f32_16x16x32_bf16(kf0, qf0, es, 0, 0, 0);
  es = __builtin_amdgcn_mfma_f32_16x16x32_bf16(kf1, qf1, es, 0, 0, 0);

  // ---- softmax over g (rows): in-lane 4 + lanes L^16, L^32.
  float s0 = es[0] * 0.125f, s1 = es[1] * 0.125f;
  float s2 = es[2] * 0.125f, s3 = es[3] * 0.125f;
  float mx = fmaxf(fmaxf(s0, s1), fmaxf(s2, s3));
  mx = fmaxf(mx, __shfl_xor(mx, 16, 64));
  mx = fmaxf(mx, __shfl_xor(mx, 32, 64));
  float e0 = __expf(s0 - mx), e1 = __expf(s1 - mx);
  float e2 = __expf(s2 - mx), e3 = __expf(s3 - mx);
  float sum = e0 + e1 + e2 + e3;
  sum += __shfl_xor(sum, 16, 64);
  sum += __shfl_xor(sum, 32, 64);
  const float inv = 1.0f / sum;

  s16x4 pa;
  pa[0] = (short)f2bf(e0 * inv);
  pa[1] = (short)f2bf(e1 * inv);
  pa[2] = (short)f2bf(e2 * inv);
  pa[3] = (short)f2bf(e3 * inv);

  // ---- PV: out[h, c*16+d'] via 4x mfma 16x16x16 (K = g = 16).
  unsigned short* Ob = O + qb;
#pragma unroll
  for (int c = 0; c < 4; ++c) {
    f32x4 o = __builtin_amdgcn_mfma_f32_16x16x16bf16_1k(pa, vb[c],
                                                        (f32x4)0.0f, 0, 0, 0);
    uint2 st;
    st.x = (uint32)f2bf(o[0]) | ((uint32)f2bf(o[1]) << 16);
    st.y = (uint32)f2bf(o[2]) | ((uint32)f2bf(o[3]) << 16);
    *(uint2*)(Ob + c * 256 + fr * 16 + kg * 4) = st;
  }
}

// ---------------- in-place LayerNorm over rows of 1024 ----------------
__global__ __launch_bounds__(256) void ln_kernel(
    float* __restrict__ Y, const float* __restrict__ gw,
    const float* __restrict__ gb) {
  float* y = Y + (size_t)blockIdx.x * 1024;
  const int tid = threadIdx.x;
  float4 v = ((const float4*)y)[tid];
  float s  = v.x + v.y + v.z + v.w;
  float s2 = v.x * v.x + v.y * v.y + v.z * v.z + v.w * v.w;
#pragma unroll
  for (int o = 32; o > 0; o >>= 1) {
    s  += __shfl_xor(s, o, 64);
    s2 += __shfl_xor(s2, o, 64);
  }
  __shared__ float rs[4], rq[4];
  const int wave = tid >> 6;
  if ((tid & 63) == 0) { rs[wave] = s; rq[wave] = s2; }
  __syncthreads();
  s  = rs[0] + rs[1] + rs[2] + rs[3];
  s2 = rq[0] + rq[1] + rq[2] + rq[3];
  const float mean = s * (1.f / 1024.f);
  const float var  = s2 * (1.f / 1024.f) - mean * mean;
  const float r = rsqrtf(var + 1e-5f);
  const float4 w = ((const float4*)gw)[tid];
  const float4 bb = ((const float4*)gb)[tid];
  float4 o;
  o.x = (v.x - mean) * r * w.x + bb.x;
  o.y = (v.y - mean) * r * w.y + bb.y;
  o.z = (v.z - mean) * r * w.z + bb.z;
  o.w = (v.w - mean) * r * w.w + bb.w;
  ((float4*)y)[tid] = o;
}

extern "C" void kernel_launch(void* const* d_in, const int* in_sizes, int n_in,
                              void* d_out, int out_size, void* d_ws,
                              size_t ws_size, hipStream_t stream) {
  const float* sa = (const float*)d_in[0];
  const float* st = (const float*)d_in[1];
  const float* Wq = (const float*)d_in[2];
  const float* bq = (const float*)d_in[3];
  const float* Wk = (const float*)d_in[4];
  const float* bk = (const float*)d_in[5];
  const float* Wv = (const float*)d_in[6];
  const float* bv = (const float*)d_in[7];
  const float* Wo = (const float*)d_in[8];
  const float* bo = (const float*)d_in[9];
  const float* lw = (const float*)d_in[10];
  const float* lb = (const float*)d_in[11];
  float* out = (float*)d_out;

  const int M = 32768, D = 1024;
  const size_t MiB = 1024 * 1024;
  char* w = (char*)d_ws;
  unsigned short* saB  = (unsigned short*)(w);                // 64 MiB
  unsigned short* stB  = (unsigned short*)(w + 64 * MiB);     // 64 MiB
  unsigned short* WqB  = (unsigned short*)(w + 128 * MiB);    // 2 MiB
  unsigned short* WkvB = (unsigned short*)(w + 130 * MiB);    // 4 MiB (Wk||Wv)
  unsigned short* WoB  = (unsigned short*)(w + 134 * MiB);    // 2 MiB
  unsigned short* Qb   = (unsigned short*)(w + 136 * MiB);    // 64 MiB -> 200 MiB
  float* bkv = (float*)(w + 128 * MiB);  // reuse WqB space (dead after Q gemm)
  // KV [M, 2048] bf16 = exactly 128 MiB -> lives in d_out (dead before O-proj)
  unsigned short* KVb = (unsigned short*)d_out;
  unsigned short* attb = saB;  // sa_bf16 dead after the Q GEMM

  const int nH8 = M * D / 8;
  const int nW8 = D * D / 8;
  cast_kernel<<<nH8 / 256, 256, 0, stream>>>(sa, saB, nH8);
  cast_kernel<<<nH8 / 256, 256, 0, stream>>>(st, stB, nH8);
  cast_kernel<<<nW8 / 256, 256, 0, stream>>>(Wq, WqB, nW8);
  cast_kernel<<<nW8 / 256, 256, 0, stream>>>(Wk, (unsigned short*)WkvB, nW8);
  cast_kernel<<<nW8 / 256, 256, 0, stream>>>(Wv, (unsigned short*)WkvB + D * D, nW8);
  cast_kernel<<<nW8 / 256, 256, 0, stream>>>(Wo, WoB, nW8);

  // Q projection: A=saB. (After this, saB and WqB space are dead.)
  gemm256<0><<<(M / 256) * (D / 256), 512, 0, stream>>>(
      saB, WqB, bq, nullptr, Qb, nullptr, M, D, D);

  // fused K+V projection: A=stB, W=[Wk;Wv], N=2048, C=KV in d_out.
  cat2_kernel<<<8, 256, 0, stream>>>(bk, bv, bkv);
  gemm256<0><<<(M / 256) * (2 * D / 256), 512, 0, stream>>>(
      stB, WkvB, bkv, nullptr, KVb, nullptr, M, 2 * D, D);

  attn_kernel<<<M / 4, 256, 0, stream>>>(Qb, KVb, attb);

  gemm256<1><<<(M / 256) * (D / 256), 512, 0, stream>>>(
      attb, WoB, bo, sa, nullptr, out, M, D, D);

  ln_kernel<<<M, 256, 0, stream>>>(out, lw, lb);
}

// Round 11
// 472.525 us; speedup vs baseline: 1.1255x; 1.1255x over previous
//
#include <hip/hip_runtime.h>

typedef unsigned int  uint32;
typedef float  f32x4   __attribute__((ext_vector_type(4)));
typedef __bf16 bf16x8  __attribute__((ext_vector_type(8)));
typedef short  s16x4   __attribute__((ext_vector_type(4)));

__device__ __forceinline__ float bf2f(unsigned int u) {
  return __builtin_bit_cast(float, u << 16);
}
__device__ __forceinline__ unsigned short f2bf(float f) {
  uint32 u = __builtin_bit_cast(uint32, f);
  u += 0x7fffu + ((u >> 16) & 1u);          // RNE
  return (unsigned short)(u >> 16);
}

__device__ __forceinline__ void gload_lds16(const void* g, void* l) {
  __builtin_amdgcn_global_load_lds(
      (const __attribute__((address_space(1))) void*)g,
      (__attribute__((address_space(3))) void*)l, 16, 0, 0);
}

// ---------------- merged fp32 -> bf16 casts (8 elems/thread) -------------
__device__ __forceinline__ void cast8(const float* __restrict__ x,
                                      unsigned short* __restrict__ y, int i) {
  const float4* xp = (const float4*)x;
  float4 a = xp[2 * i], b = xp[2 * i + 1];
  uint4 o;
  o.x = (uint32)f2bf(a.x) | ((uint32)f2bf(a.y) << 16);
  o.y = (uint32)f2bf(a.z) | ((uint32)f2bf(a.w) << 16);
  o.z = (uint32)f2bf(b.x) | ((uint32)f2bf(b.y) << 16);
  o.w = (uint32)f2bf(b.z) | ((uint32)f2bf(b.w) << 16);
  ((uint4*)y)[i] = o;
}

__global__ __launch_bounds__(256) void prep_kernel(
    const float* __restrict__ sa, const float* __restrict__ st,
    const float* __restrict__ Wq, const float* __restrict__ Wk,
    const float* __restrict__ Wv, const float* __restrict__ Wo,
    unsigned short* __restrict__ saB, unsigned short* __restrict__ stB,
    unsigned short* __restrict__ WqB, unsigned short* __restrict__ WkvB,
    unsigned short* __restrict__ WoB, int nH8, int nW8) {
  int i = blockIdx.x * 256 + threadIdx.x;       // block-uniform ranges
  if (i < nH8) { cast8(sa, saB, i); return; }
  i -= nH8;
  if (i < nH8) { cast8(st, stB, i); return; }
  i -= nH8;
  if (i < nW8) { cast8(Wq, WqB, i); return; }
  i -= nW8;
  if (i < nW8) { cast8(Wk, WkvB, i); return; }
  i -= nW8;
  if (i < nW8) { cast8(Wv, WkvB + (size_t)nW8 * 8, i); return; }
  i -= nW8;
  cast8(Wo, WoB, i);
}

// ------- bf16 GEMM body: C[M,N] = bf16(A[M,K] * W[N,K]^T + bias) -------
// Proven round-9 engine, verbatim (only gridDim/blockIdx -> nwg/bid params,
// and block-uniform split-bias select for the fused KV problem).
// 256x256 tile, BK=64, 8 waves (2M x 4N), TWO LDS buffers (2 x 64KB),
// 2-tile-deep prefetch with counted vmcnt(8), raw s_barrier,
// st_16x32-style XOR swizzle (row 128B: chunk16 ^= row&7).
__device__ __forceinline__ void gemm_body(
    const unsigned short* __restrict__ A, const unsigned short* __restrict__ W,
    const float* __restrict__ bias, const float* __restrict__ bias2,
    unsigned short* __restrict__ Ob,
    int M, int N, int K, int nwg, int bid, char* smem) {
  const int tid  = threadIdx.x;
  const int lane = tid & 63;
  const int wave = tid >> 6;      // 0..7
  const int wr   = wave >> 2;     // 0..1 : m half (128 rows)
  const int wc   = wave & 3;      // 0..3 : n quarter (64 cols)

  // XCD chunk (bijective, nwg%8==0): n-fastest within chunk for A L2-reuse.
  const int xcd = bid & 7;
  const int r   = bid >> 3;                 // 0 .. nwg/8-1
  const int NT  = N >> 8;                   // n-tiles
  const int m0  = (xcd * ((nwg >> 3) / NT) + r / NT) << 8;
  const int n0  = (r % NT) << 8;

  f32x4 acc[8][4];
#pragma unroll
  for (int m = 0; m < 8; ++m)
#pragma unroll
    for (int n = 0; n < 4; ++n) acc[m][n] = (f32x4)0.0f;

  // ---- staging geometry (inverse-swizzled global source, linear LDS dest).
  const int pr8 = lane >> 3;
  const int cl  = (lane & 7) ^ pr8;
  const unsigned short* As = A + (size_t)(m0 + wave * 8 + pr8) * K + cl * 8;
  const unsigned short* Bs = W + (size_t)(n0 + wave * 8 + pr8) * K + cl * 8;
  const int dst = wave * 1024 + lane * 16;

#define STAGE(d, kt)                                                          \
  {                                                                           \
    char* sb = smem + (d) * 65536;                                            \
    const int ko = (kt) * 64;                                                 \
    _Pragma("unroll") for (int j = 0; j < 4; ++j)                             \
        gload_lds16(As + (size_t)(j * 64) * K + ko, sb + j * 8192 + dst);     \
    _Pragma("unroll") for (int j = 0; j < 4; ++j)                             \
        gload_lds16(Bs + (size_t)(j * 64) * K + ko,                           \
                    sb + 32768 + j * 8192 + dst);                             \
  }

  // ---- fragment read offsets (swizzled): row r, k-chunk c (= ks*4+kg):
  // byte = r*128 + ((c ^ (r&7))*16.
  const int fr = lane & 15, kg = lane >> 4;
  int cA[2];
#pragma unroll
  for (int ks = 0; ks < 2; ++ks)
    cA[ks] = fr * 128 + (((ks * 4 + kg) ^ (fr & 7)) * 16);
  const int abase = wr * 16384;           // + m*2048 + cA[ks]
  const int bbase = 32768 + wc * 8192;    // + n*2048 + cA[ks]

#define PH_AB(base_, av_, bv_, mlo, ks)                                       \
  {                                                                           \
    _Pragma("unroll") for (int m = 0; m < 4; ++m)                             \
        av_[m] = *(const bf16x8*)((base_) + abase + ((mlo) + m) * 2048 +      \
                                  cA[ks]);                                    \
    _Pragma("unroll") for (int n = 0; n < 4; ++n)                             \
        bv_[n] = *(const bf16x8*)((base_) + bbase + n * 2048 + cA[ks]);       \
  }
#define PH_A(base_, av_, mlo, ks)                                             \
  {                                                                           \
    _Pragma("unroll") for (int m = 0; m < 4; ++m)                             \
        av_[m] = *(const bf16x8*)((base_) + abase + ((mlo) + m) * 2048 +      \
                                  cA[ks]);                                    \
  }
#define PH_MFMA(av_, bv_, mlo)                                                \
  __builtin_amdgcn_s_setprio(1);                                              \
  _Pragma("unroll") for (int m = 0; m < 4; ++m)                               \
      _Pragma("unroll") for (int n = 0; n < 4; ++n)                           \
          acc[(mlo) + m][n] = __builtin_amdgcn_mfma_f32_16x16x32_bf16(        \
              av_[m], bv_[n], acc[(mlo) + m][n], 0, 0, 0);                    \
  __builtin_amdgcn_s_setprio(0);

  const int nt = K >> 6;  // 64-wide K-tiles
  STAGE(0, 0);
  STAGE(1, 1);

  for (int t = 0; t < nt - 2; ++t) {
    // in flight: t (8) + t+1 (8).  Drain to 8 -> tile t landed.
    asm volatile("s_waitcnt vmcnt(8)" ::: "memory");
    __builtin_amdgcn_s_barrier();
    const char* base = smem + (t & 1) * 65536;
    bf16x8 a0[4], a1[4], b0[4], b1[4];
    PH_AB(base, a0, b0, 0, 0);
    PH_MFMA(a0, b0, 0);
    PH_A(base, a1, 4, 0);
    PH_MFMA(a1, b0, 4);
    PH_AB(base, a0, b1, 0, 1);
    PH_MFMA(a0, b1, 0);
    PH_A(base, a1, 4, 1);
    asm volatile("s_waitcnt lgkmcnt(0)" ::: "memory");
    __builtin_amdgcn_s_barrier();          // all waves done reading buf
    STAGE(t & 1, t + 2);                   // overwrite with tile t+2
    __builtin_amdgcn_sched_barrier(0);
    PH_MFMA(a1, b1, 4);
  }
  // tail: tiles nt-2 (vmcnt 8) and nt-1 (vmcnt 0), no staging
#pragma unroll
  for (int tt = 0; tt < 2; ++tt) {
    if (tt == 0)
      asm volatile("s_waitcnt vmcnt(8)" ::: "memory");
    else
      asm volatile("s_waitcnt vmcnt(0)" ::: "memory");
    __builtin_amdgcn_s_barrier();
    const char* base = smem + ((nt - 2 + tt) & 1) * 65536;
    bf16x8 a0[4], a1[4], b0[4], b1[4];
    PH_AB(base, a0, b0, 0, 0);
    PH_MFMA(a0, b0, 0);
    PH_A(base, a1, 4, 0);
    PH_MFMA(a1, b0, 4);
    PH_AB(base, a0, b1, 0, 1);
    PH_MFMA(a0, b1, 0);
    PH_A(base, a1, 4, 1);
    PH_MFMA(a1, b1, 4);
  }

  // ---- epilogue: C/D map col = lane&15, row = (lane>>4)*4 + i.
  // Row-major store order so each row's 4 chunks issue back-to-back.
  // Split bias (fused KV problem): block-uniform n0 decides bk vs bv.
  const float* bsel = (bias2 != nullptr && n0 >= 1024) ? (bias2 - 1024) : bias;
  const int r4 = (lane >> 4) * 4;
  float bvv[4];
#pragma unroll
  for (int n = 0; n < 4; ++n) bvv[n] = bsel[n0 + wc * 64 + n * 16 + fr];
#pragma unroll
  for (int m = 0; m < 8; ++m) {
    const int rowb = m0 + wr * 128 + m * 16 + r4;
#pragma unroll
    for (int i = 0; i < 4; ++i) {
      const size_t rb = (size_t)(rowb + i) * N;
#pragma unroll
      for (int n = 0; n < 4; ++n) {
        const size_t idx = rb + (n0 + wc * 64 + n * 16 + fr);
        Ob[idx] = f2bf(acc[m][n][i] + bvv[n]);
      }
    }
  }
#undef STAGE
#undef PH_AB
#undef PH_A
#undef PH_MFMA
}

// ---- grouped Q-proj + KV-proj in one dispatch (blocks [0,nb0) -> Q) ----
__global__ __launch_bounds__(512, 2) void gemm_qkv(
    const unsigned short* A0, const unsigned short* W0, const float* b0,
    unsigned short* C0, int N0, int nb0,
    const unsigned short* A1, const unsigned short* W1, const float* b1lo,
    const float* b1hi, unsigned short* C1, int N1, int M, int K) {
  __shared__ char smem[131072];  // 2 bufs x (A 32KB | B 32KB)
  if ((int)blockIdx.x < nb0)
    gemm_body(A0, W0, b0, nullptr, C0, M, N0, K, nb0, blockIdx.x, smem);
  else
    gemm_body(A1, W1, b1lo, b1hi, C1, M, N1, K, gridDim.x - nb0,
              blockIdx.x - nb0, smem);
}

// ---- O-projection: bf16 out (no residual -- fused into ln2) ----
__global__ __launch_bounds__(512, 2) void gemm_o(
    const unsigned short* A, const unsigned short* W, const float* bias,
    unsigned short* C, int M, int N, int K) {
  __shared__ char smem[131072];
  gemm_body(A, W, bias, nullptr, C, M, N, K, gridDim.x, blockIdx.x, smem);
}

// ---------------- head-wise attention, MFMA, one wave per row b ----------
// Q: [B,1024].  K,V packed in KV [B,2048]: K at +0, V at +1024.
// Out: [B,1024] with idx = d*16 + h.
__global__ __launch_bounds__(256) void attn_kernel(
    const unsigned short* __restrict__ Q, const unsigned short* __restrict__ KV,
    unsigned short* __restrict__ O) {
  const int tid  = threadIdx.x;
  const int lane = tid & 63;
  const int wave = tid >> 6;
  const int b    = blockIdx.x * 4 + wave;
  const size_t qb  = (size_t)b * 1024;
  const size_t kvb = (size_t)b * 2048;
  const int fr = lane & 15, kg = lane >> 4;

  // ---- QK^T (transposed): A = K rows (g), B = Q rows (h), K-dim = d (64).
  const bf16x8 kf0 = *(const bf16x8*)(KV + kvb + fr * 64 + kg * 8);
  const bf16x8 kf1 = *(const bf16x8*)(KV + kvb + fr * 64 + 32 + kg * 8);
  const bf16x8 qf0 = *(const bf16x8*)(Q + qb + fr * 64 + kg * 8);
  const bf16x8 qf1 = *(const bf16x8*)(Q + qb + fr * 64 + 32 + kg * 8);

  // ---- V B-fragments: lane (fr=d_local, kg) holds V[kg*4+j][c*16+fr].
  s16x4 vb[4];
#pragma unroll
  for (int c = 0; c < 4; ++c) {
    const unsigned short* vp = KV + kvb + 1024 + c * 16 + fr + kg * 4 * 64;
    s16x4 t;
    t[0] = (short)vp[0];
    t[1] = (short)vp[64];
    t[2] = (short)vp[128];
    t[3] = (short)vp[192];
    vb[c] = t;
  }

  f32x4 es = (f32x4)0.0f;
  es = __builtin_amdgcn_mfma_f32_16x16x32_bf16(kf0, qf0, es, 0, 0, 0);
  es = __builtin_amdgcn_mfma_f32_16x16x32_bf16(kf1, qf1, es, 0, 0, 0);

  // ---- softmax over g (rows): in-lane 4 + lanes L^16, L^32.
  float s0 = es[0] * 0.125f, s1 = es[1] * 0.125f;
  float s2 = es[2] * 0.125f, s3 = es[3] * 0.125f;
  float mx = fmaxf(fmaxf(s0, s1), fmaxf(s2, s3));
  mx = fmaxf(mx, __shfl_xor(mx, 16, 64));
  mx = fmaxf(mx, __shfl_xor(mx, 32, 64));
  float e0 = __expf(s0 - mx), e1 = __expf(s1 - mx);
  float e2 = __expf(s2 - mx), e3 = __expf(s3 - mx);
  float sum = e0 + e1 + e2 + e3;
  sum += __shfl_xor(sum, 16, 64);
  sum += __shfl_xor(sum, 32, 64);
  const float inv = 1.0f / sum;

  s16x4 pa;
  pa[0] = (short)f2bf(e0 * inv);
  pa[1] = (short)f2bf(e1 * inv);
  pa[2] = (short)f2bf(e2 * inv);
  pa[3] = (short)f2bf(e3 * inv);

  // ---- PV: out[h, c*16+d'] via 4x mfma 16x16x16 (K = g = 16).
  unsigned short* Ob = O + qb;
#pragma unroll
  for (int c = 0; c < 4; ++c) {
    f32x4 o = __builtin_amdgcn_mfma_f32_16x16x16bf16_1k(pa, vb[c],
                                                        (f32x4)0.0f, 0, 0, 0);
    uint2 st;
    st.x = (uint32)f2bf(o[0]) | ((uint32)f2bf(o[1]) << 16);
    st.y = (uint32)f2bf(o[2]) | ((uint32)f2bf(o[3]) << 16);
    *(uint2*)(Ob + c * 256 + fr * 16 + kg * 4) = st;
  }
}

// ------- fused residual + LayerNorm: Y = LN(bf16(oproj) + sa) -------
__global__ __launch_bounds__(256) void ln2_kernel(
    const unsigned short* __restrict__ Ob, const float* __restrict__ sa,
    float* __restrict__ Y, const float* __restrict__ gw,
    const float* __restrict__ gb) {
  const size_t rb = (size_t)blockIdx.x * 1024;
  const int tid = threadIdx.x;
  const uint2 ov = ((const uint2*)(Ob + rb))[tid];         // 4 bf16
  const float4 sv = ((const float4*)(sa + rb))[tid];
  float4 v;
  v.x = bf2f(ov.x & 0xffff) + sv.x;
  v.y = bf2f(ov.x >> 16) + sv.y;
  v.z = bf2f(ov.y & 0xffff) + sv.z;
  v.w = bf2f(ov.y >> 16) + sv.w;
  float s  = v.x + v.y + v.z + v.w;
  float s2 = v.x * v.x + v.y * v.y + v.z * v.z + v.w * v.w;
#pragma unroll
  for (int o = 32; o > 0; o >>= 1) {
    s  += __shfl_xor(s, o, 64);
    s2 += __shfl_xor(s2, o, 64);
  }
  __shared__ float rs[4], rq[4];
  const int wave = tid >> 6;
  if ((tid & 63) == 0) { rs[wave] = s; rq[wave] = s2; }
  __syncthreads();
  s  = rs[0] + rs[1] + rs[2] + rs[3];
  s2 = rq[0] + rq[1] + rq[2] + rq[3];
  const float mean = s * (1.f / 1024.f);
  const float var  = s2 * (1.f / 1024.f) - mean * mean;
  const float r = rsqrtf(var + 1e-5f);
  const float4 w = ((const float4*)gw)[tid];
  const float4 bb = ((const float4*)gb)[tid];
  float4 o;
  o.x = (v.x - mean) * r * w.x + bb.x;
  o.y = (v.y - mean) * r * w.y + bb.y;
  o.z = (v.z - mean) * r * w.z + bb.z;
  o.w = (v.w - mean) * r * w.w + bb.w;
  ((float4*)(Y + rb))[tid] = o;
}

extern "C" void kernel_launch(void* const* d_in, const int* in_sizes, int n_in,
                              void* d_out, int out_size, void* d_ws,
                              size_t ws_size, hipStream_t stream) {
  const float* sa = (const float*)d_in[0];
  const float* st = (const float*)d_in[1];
  const float* Wq = (const float*)d_in[2];
  const float* bq = (const float*)d_in[3];
  const float* Wk = (const float*)d_in[4];
  const float* bk = (const float*)d_in[5];
  const float* Wv = (const float*)d_in[6];
  const float* bv = (const float*)d_in[7];
  const float* Wo = (const float*)d_in[8];
  const float* bo = (const float*)d_in[9];
  const float* lw = (const float*)d_in[10];
  const float* lb = (const float*)d_in[11];
  float* out = (float*)d_out;

  const int M = 32768, D = 1024;
  const size_t MiB = 1024 * 1024;
  char* w = (char*)d_ws;
  unsigned short* saB  = (unsigned short*)(w);                // 64 MiB
  unsigned short* stB  = (unsigned short*)(w + 64 * MiB);     // 64 MiB
  unsigned short* WqB  = (unsigned short*)(w + 128 * MiB);    // 2 MiB
  unsigned short* WkvB = (unsigned short*)(w + 130 * MiB);    // 4 MiB (Wk||Wv)
  unsigned short* WoB  = (unsigned short*)(w + 134 * MiB);    // 2 MiB
  unsigned short* Qb   = (unsigned short*)(w + 136 * MiB);    // 64 MiB -> 200
  // KV [M,2048] bf16 = 128 MiB -> d_out (dead before ln2 writes it).
  unsigned short* KVb = (unsigned short*)d_out;
  unsigned short* attb = saB;  // saB dead after Q-proj (same dispatch group)
  unsigned short* oB   = stB;  // stB dead after KV-proj

  const int nH8 = M * D / 8;   // 4,194,304
  const int nW8 = D * D / 8;   // 131,072
  // 1) all casts in one dispatch
  prep_kernel<<<(2 * nH8 + 4 * nW8) / 256, 256, 0, stream>>>(
      sa, st, Wq, Wk, Wv, Wo, saB, stB, WqB, WkvB, WoB, nH8, nW8);

  // 2) grouped Q-proj (512 blocks) + fused K/V-proj (1024 blocks)
  const int nbQ  = (M / 256) * (D / 256);        // 512
  const int nbKV = (M / 256) * (2 * D / 256);    // 1024
  gemm_qkv<<<nbQ + nbKV, 512, 0, stream>>>(
      saB, WqB, bq, Qb, D, nbQ,
      stB, WkvB, bk, bv, KVb, 2 * D, M, D);

  // 3) attention
  attn_kernel<<<M / 4, 256, 0, stream>>>(Qb, KVb, attb);

  // 4) O-projection -> bf16 scratch (residual deferred to ln2)
  gemm_o<<<nbQ, 512, 0, stream>>>(attb, WoB, bo, oB, M, D, D);

  // 5) fused residual + LayerNorm -> d_out
  ln2_kernel<<<M, 256, 0, stream>>>(oB, sa, out, lw, lb);
}

// Round 12
// 459.703 us; speedup vs baseline: 1.1569x; 1.0279x over previous
//
#include <hip/hip_runtime.h>

typedef unsigned int  uint32;
typedef float  f32x4   __attribute__((ext_vector_type(4)));
typedef __bf16 bf16x8  __attribute__((ext_vector_type(8)));
typedef short  s16x4   __attribute__((ext_vector_type(4)));

__device__ __forceinline__ float bf2f(unsigned int u) {
  return __builtin_bit_cast(float, u << 16);
}
__device__ __forceinline__ unsigned short f2bf(float f) {
  uint32 u = __builtin_bit_cast(uint32, f);
  u += 0x7fffu + ((u >> 16) & 1u);          // RNE
  return (unsigned short)(u >> 16);
}

__device__ __forceinline__ void gload_lds16(const void* g, void* l) {
  __builtin_amdgcn_global_load_lds(
      (const __attribute__((address_space(1))) void*)g,
      (__attribute__((address_space(3))) void*)l, 16, 0, 0);
}

// ---------------- merged fp32 -> bf16 casts (8 elems/thread) -------------
__device__ __forceinline__ void cast8(const float* __restrict__ x,
                                      unsigned short* __restrict__ y, int i) {
  const float4* xp = (const float4*)x;
  float4 a = xp[2 * i], b = xp[2 * i + 1];
  uint4 o;
  o.x = (uint32)f2bf(a.x) | ((uint32)f2bf(a.y) << 16);
  o.y = (uint32)f2bf(a.z) | ((uint32)f2bf(a.w) << 16);
  o.z = (uint32)f2bf(b.x) | ((uint32)f2bf(b.y) << 16);
  o.w = (uint32)f2bf(b.z) | ((uint32)f2bf(b.w) << 16);
  ((uint4*)y)[i] = o;
}

__global__ __launch_bounds__(256) void prep_kernel(
    const float* __restrict__ sa, const float* __restrict__ st,
    const float* __restrict__ Wq, const float* __restrict__ Wk,
    const float* __restrict__ Wv, const float* __restrict__ Wo,
    unsigned short* __restrict__ saB, unsigned short* __restrict__ stB,
    unsigned short* __restrict__ WqB, unsigned short* __restrict__ WkvB,
    unsigned short* __restrict__ WoB, int nH8, int nW8) {
  int i = blockIdx.x * 256 + threadIdx.x;       // block-uniform ranges
  if (i < nH8) { cast8(sa, saB, i); return; }
  i -= nH8;
  if (i < nH8) { cast8(st, stB, i); return; }
  i -= nH8;
  if (i < nW8) { cast8(Wq, WqB, i); return; }
  i -= nW8;
  if (i < nW8) { cast8(Wk, WkvB, i); return; }
  i -= nW8;
  if (i < nW8) { cast8(Wv, WkvB + (size_t)nW8 * 8, i); return; }
  i -= nW8;
  cast8(Wo, WoB, i);
}

// ------- bf16 GEMM body: C[M,N] = bf16(A[M,K] * W[N,K]^T + bias) -------
// Proven round-9 engine, verbatim.
// 256x256 tile, BK=64, 8 waves (2M x 4N), TWO LDS buffers (2 x 64KB),
// 2-tile-deep prefetch with counted vmcnt(8), raw s_barrier,
// st_16x32-style XOR swizzle (row 128B: chunk16 ^= row&7).
__device__ __forceinline__ void gemm_body(
    const unsigned short* __restrict__ A, const unsigned short* __restrict__ W,
    const float* __restrict__ bias, const float* __restrict__ bias2,
    unsigned short* __restrict__ Ob,
    int M, int N, int K, int nwg, int bid, char* smem) {
  const int tid  = threadIdx.x;
  const int lane = tid & 63;
  const int wave = tid >> 6;      // 0..7
  const int wr   = wave >> 2;     // 0..1 : m half (128 rows)
  const int wc   = wave & 3;      // 0..3 : n quarter (64 cols)

  // XCD chunk (bijective, nwg%8==0): n-fastest within chunk for A L2-reuse.
  const int xcd = bid & 7;
  const int r   = bid >> 3;                 // 0 .. nwg/8-1
  const int NT  = N >> 8;                   // n-tiles
  const int m0  = (xcd * ((nwg >> 3) / NT) + r / NT) << 8;
  const int n0  = (r % NT) << 8;

  f32x4 acc[8][4];
#pragma unroll
  for (int m = 0; m < 8; ++m)
#pragma unroll
    for (int n = 0; n < 4; ++n) acc[m][n] = (f32x4)0.0f;

  // ---- staging geometry (inverse-swizzled global source, linear LDS dest).
  const int pr8 = lane >> 3;
  const int cl  = (lane & 7) ^ pr8;
  const unsigned short* As = A + (size_t)(m0 + wave * 8 + pr8) * K + cl * 8;
  const unsigned short* Bs = W + (size_t)(n0 + wave * 8 + pr8) * K + cl * 8;
  const int dst = wave * 1024 + lane * 16;

#define STAGE(d, kt)                                                          \
  {                                                                           \
    char* sb = smem + (d) * 65536;                                            \
    const int ko = (kt) * 64;                                                 \
    _Pragma("unroll") for (int j = 0; j < 4; ++j)                             \
        gload_lds16(As + (size_t)(j * 64) * K + ko, sb + j * 8192 + dst);     \
    _Pragma("unroll") for (int j = 0; j < 4; ++j)                             \
        gload_lds16(Bs + (size_t)(j * 64) * K + ko,                           \
                    sb + 32768 + j * 8192 + dst);                             \
  }

  // ---- fragment read offsets (swizzled): row r, k-chunk c (= ks*4+kg):
  // byte = r*128 + ((c ^ (r&7))*16.
  const int fr = lane & 15, kg = lane >> 4;
  int cA[2];
#pragma unroll
  for (int ks = 0; ks < 2; ++ks)
    cA[ks] = fr * 128 + (((ks * 4 + kg) ^ (fr & 7)) * 16);
  const int abase = wr * 16384;           // + m*2048 + cA[ks]
  const int bbase = 32768 + wc * 8192;    // + n*2048 + cA[ks]

#define PH_AB(base_, av_, bv_, mlo, ks)                                       \
  {                                                                           \
    _Pragma("unroll") for (int m = 0; m < 4; ++m)                             \
        av_[m] = *(const bf16x8*)((base_) + abase + ((mlo) + m) * 2048 +      \
                                  cA[ks]);                                    \
    _Pragma("unroll") for (int n = 0; n < 4; ++n)                             \
        bv_[n] = *(const bf16x8*)((base_) + bbase + n * 2048 + cA[ks]);       \
  }
#define PH_A(base_, av_, mlo, ks)                                             \
  {                                                                           \
    _Pragma("unroll") for (int m = 0; m < 4; ++m)                             \
        av_[m] = *(const bf16x8*)((base_) + abase + ((mlo) + m) * 2048 +      \
                                  cA[ks]);                                    \
  }
#define PH_MFMA(av_, bv_, mlo)                                                \
  __builtin_amdgcn_s_setprio(1);                                              \
  _Pragma("unroll") for (int m = 0; m < 4; ++m)                               \
      _Pragma("unroll") for (int n = 0; n < 4; ++n)                           \
          acc[(mlo) + m][n] = __builtin_amdgcn_mfma_f32_16x16x32_bf16(        \
              av_[m], bv_[n], acc[(mlo) + m][n], 0, 0, 0);                    \
  __builtin_amdgcn_s_setprio(0);

  const int nt = K >> 6;  // 64-wide K-tiles
  STAGE(0, 0);
  STAGE(1, 1);

  for (int t = 0; t < nt - 2; ++t) {
    // in flight: t (8) + t+1 (8).  Drain to 8 -> tile t landed.
    asm volatile("s_waitcnt vmcnt(8)" ::: "memory");
    __builtin_amdgcn_s_barrier();
    const char* base = smem + (t & 1) * 65536;
    bf16x8 a0[4], a1[4], b0[4], b1[4];
    PH_AB(base, a0, b0, 0, 0);
    PH_MFMA(a0, b0, 0);
    PH_A(base, a1, 4, 0);
    PH_MFMA(a1, b0, 4);
    PH_AB(base, a0, b1, 0, 1);
    PH_MFMA(a0, b1, 0);
    PH_A(base, a1, 4, 1);
    asm volatile("s_waitcnt lgkmcnt(0)" ::: "memory");
    __builtin_amdgcn_s_barrier();          // all waves done reading buf
    STAGE(t & 1, t + 2);                   // overwrite with tile t+2
    __builtin_amdgcn_sched_barrier(0);
    PH_MFMA(a1, b1, 4);
  }
  // tail: tiles nt-2 (vmcnt 8) and nt-1 (vmcnt 0), no staging
#pragma unroll
  for (int tt = 0; tt < 2; ++tt) {
    if (tt == 0)
      asm volatile("s_waitcnt vmcnt(8)" ::: "memory");
    else
      asm volatile("s_waitcnt vmcnt(0)" ::: "memory");
    __builtin_amdgcn_s_barrier();
    const char* base = smem + ((nt - 2 + tt) & 1) * 65536;
    bf16x8 a0[4], a1[4], b0[4], b1[4];
    PH_AB(base, a0, b0, 0, 0);
    PH_MFMA(a0, b0, 0);
    PH_A(base, a1, 4, 0);
    PH_MFMA(a1, b0, 4);
    PH_AB(base, a0, b1, 0, 1);
    PH_MFMA(a0, b1, 0);
    PH_A(base, a1, 4, 1);
    PH_MFMA(a1, b1, 4);
  }

  // ---- epilogue: C/D map col = lane&15, row = (lane>>4)*4 + i.
  // Row-major store order so each row's 4 chunks issue back-to-back.
  // Split bias (fused KV problem): block-uniform n0 decides bk vs bv.
  const float* bsel = (bias2 != nullptr && n0 >= 1024) ? (bias2 - 1024) : bias;
  const int r4 = (lane >> 4) * 4;
  float bvv[4];
#pragma unroll
  for (int n = 0; n < 4; ++n) bvv[n] = bsel[n0 + wc * 64 + n * 16 + fr];
#pragma unroll
  for (int m = 0; m < 8; ++m) {
    const int rowb = m0 + wr * 128 + m * 16 + r4;
#pragma unroll
    for (int i = 0; i < 4; ++i) {
      const size_t rb = (size_t)(rowb + i) * N;
#pragma unroll
      for (int n = 0; n < 4; ++n) {
        const size_t idx = rb + (n0 + wc * 64 + n * 16 + fr);
        Ob[idx] = f2bf(acc[m][n][i] + bvv[n]);
      }
    }
  }
#undef STAGE
#undef PH_AB
#undef PH_A
#undef PH_MFMA
}

// ---- grouped Q-proj + KV-proj in one dispatch (blocks [0,nb0) -> Q) ----
__global__ __launch_bounds__(512, 2) void gemm_qkv(
    const unsigned short* A0, const unsigned short* W0, const float* b0,
    unsigned short* C0, int N0, int nb0,
    const unsigned short* A1, const unsigned short* W1, const float* b1lo,
    const float* b1hi, unsigned short* C1, int N1, int M, int K) {
  __shared__ char smem[131072];  // 2 bufs x (A 32KB | B 32KB)
  if ((int)blockIdx.x < nb0)
    gemm_body(A0, W0, b0, nullptr, C0, M, N0, K, nb0, blockIdx.x, smem);
  else
    gemm_body(A1, W1, b1lo, b1hi, C1, M, N1, K, gridDim.x - nb0,
              blockIdx.x - nb0, smem);
}

// ---- O-projection: bf16 out (residual fused into ln2) ----
__global__ __launch_bounds__(512, 2) void gemm_o(
    const unsigned short* A, const unsigned short* W, const float* bias,
    unsigned short* C, int M, int N, int K) {
  __shared__ char smem[131072];
  gemm_body(A, W, bias, nullptr, C, M, N, K, gridDim.x, blockIdx.x, smem);
}

// ---------------- head-wise attention, MFMA, one wave per row b ----------
// Q: [B,1024].  K,V packed in KV [B,2048]: K at +0, V at +1024.
// Out: [B,1024] with idx = d*16 + h.  O may ALIAS Q (in-place): each wave
// fully loads its row's Q into registers before any store (per-row RAW via
// data flow), and waves touch disjoint rows.
__global__ __launch_bounds__(256) void attn_kernel(
    const unsigned short* __restrict__ Q, const unsigned short* __restrict__ KV,
    unsigned short* __restrict__ O) {
  const int tid  = threadIdx.x;
  const int lane = tid & 63;
  const int wave = tid >> 6;
  const int b    = blockIdx.x * 4 + wave;
  const size_t qb  = (size_t)b * 1024;
  const size_t kvb = (size_t)b * 2048;
  const int fr = lane & 15, kg = lane >> 4;

  // ---- QK^T (transposed): A = K rows (g), B = Q rows (h), K-dim = d (64).
  const bf16x8 kf0 = *(const bf16x8*)(KV + kvb + fr * 64 + kg * 8);
  const bf16x8 kf1 = *(const bf16x8*)(KV + kvb + fr * 64 + 32 + kg * 8);
  const bf16x8 qf0 = *(const bf16x8*)(Q + qb + fr * 64 + kg * 8);
  const bf16x8 qf1 = *(const bf16x8*)(Q + qb + fr * 64 + 32 + kg * 8);

  // ---- V B-fragments: lane (fr=d_local, kg) holds V[kg*4+j][c*16+fr].
  s16x4 vb[4];
#pragma unroll
  for (int c = 0; c < 4; ++c) {
    const unsigned short* vp = KV + kvb + 1024 + c * 16 + fr + kg * 4 * 64;
    s16x4 t;
    t[0] = (short)vp[0];
    t[1] = (short)vp[64];
    t[2] = (short)vp[128];
    t[3] = (short)vp[192];
    vb[c] = t;
  }

  f32x4 es = (f32x4)0.0f;
  es = __builtin_amdgcn_mfma_f32_16x16x32_bf16(kf0, qf0, es, 0, 0, 0);
  es = __builtin_amdgcn_mfma_f32_16x16x32_bf16(kf1, qf1, es, 0, 0, 0);

  // ---- softmax over g (rows): in-lane 4 + lanes L^16, L^32.
  float s0 = es[0] * 0.125f, s1 = es[1] * 0.125f;
  float s2 = es[2] * 0.125f, s3 = es[3] * 0.125f;
  float mx = fmaxf(fmaxf(s0, s1), fmaxf(s2, s3));
  mx = fmaxf(mx, __shfl_xor(mx, 16, 64));
  mx = fmaxf(mx, __shfl_xor(mx, 32, 64));
  float e0 = __expf(s0 - mx), e1 = __expf(s1 - mx);
  float e2 = __expf(s2 - mx), e3 = __expf(s3 - mx);
  float sum = e0 + e1 + e2 + e3;
  sum += __shfl_xor(sum, 16, 64);
  sum += __shfl_xor(sum, 32, 64);
  const float inv = 1.0f / sum;

  s16x4 pa;
  pa[0] = (short)f2bf(e0 * inv);
  pa[1] = (short)f2bf(e1 * inv);
  pa[2] = (short)f2bf(e2 * inv);
  pa[3] = (short)f2bf(e3 * inv);

  // ---- PV: out[h, c*16+d'] via 4x mfma 16x16x16 (K = g = 16).
  unsigned short* Ob = O + qb;
#pragma unroll
  for (int c = 0; c < 4; ++c) {
    f32x4 o = __builtin_amdgcn_mfma_f32_16x16x16bf16_1k(pa, vb[c],
                                                        (f32x4)0.0f, 0, 0, 0);
    uint2 st;
    st.x = (uint32)f2bf(o[0]) | ((uint32)f2bf(o[1]) << 16);
    st.y = (uint32)f2bf(o[2]) | ((uint32)f2bf(o[3]) << 16);
    *(uint2*)(Ob + c * 256 + fr * 16 + kg * 4) = st;
  }
}

// --- fused residual + LayerNorm: Y = LN(bf16(oproj) + bf16(sa)) ---
__global__ __launch_bounds__(256) void ln2_kernel(
    const unsigned short* __restrict__ Ob,
    const unsigned short* __restrict__ saB, float* __restrict__ Y,
    const float* __restrict__ gw, const float* __restrict__ gb) {
  const size_t rb = (size_t)blockIdx.x * 1024;
  const int tid = threadIdx.x;
  const uint2 ov = ((const uint2*)(Ob + rb))[tid];          // 4 bf16
  const uint2 sv = ((const uint2*)(saB + rb))[tid];         // 4 bf16
  float4 v;
  v.x = bf2f(ov.x & 0xffff) + bf2f(sv.x & 0xffff);
  v.y = bf2f(ov.x >> 16)    + bf2f(sv.x >> 16);
  v.z = bf2f(ov.y & 0xffff) + bf2f(sv.y & 0xffff);
  v.w = bf2f(ov.y >> 16)    + bf2f(sv.y >> 16);
  float s  = v.x + v.y + v.z + v.w;
  float s2 = v.x * v.x + v.y * v.y + v.z * v.z + v.w * v.w;
#pragma unroll
  for (int o = 32; o > 0; o >>= 1) {
    s  += __shfl_xor(s, o, 64);
    s2 += __shfl_xor(s2, o, 64);
  }
  __shared__ float rs[4], rq[4];
  const int wave = tid >> 6;
  if ((tid & 63) == 0) { rs[wave] = s; rq[wave] = s2; }
  __syncthreads();
  s  = rs[0] + rs[1] + rs[2] + rs[3];
  s2 = rq[0] + rq[1] + rq[2] + rq[3];
  const float mean = s * (1.f / 1024.f);
  const float var  = s2 * (1.f / 1024.f) - mean * mean;
  const float r = rsqrtf(var + 1e-5f);
  const float4 w = ((const float4*)gw)[tid];
  const float4 bb = ((const float4*)gb)[tid];
  float4 o;
  o.x = (v.x - mean) * r * w.x + bb.x;
  o.y = (v.y - mean) * r * w.y + bb.y;
  o.z = (v.z - mean) * r * w.z + bb.z;
  o.w = (v.w - mean) * r * w.w + bb.w;
  ((float4*)(Y + rb))[tid] = o;
}

extern "C" void kernel_launch(void* const* d_in, const int* in_sizes, int n_in,
                              void* d_out, int out_size, void* d_ws,
                              size_t ws_size, hipStream_t stream) {
  const float* sa = (const float*)d_in[0];
  const float* st = (const float*)d_in[1];
  const float* Wq = (const float*)d_in[2];
  const float* bq = (const float*)d_in[3];
  const float* Wk = (const float*)d_in[4];
  const float* bk = (const float*)d_in[5];
  const float* Wv = (const float*)d_in[6];
  const float* bv = (const float*)d_in[7];
  const float* Wo = (const float*)d_in[8];
  const float* bo = (const float*)d_in[9];
  const float* lw = (const float*)d_in[10];
  const float* lb = (const float*)d_in[11];
  float* out = (float*)d_out;

  const int M = 32768, D = 1024;
  const size_t MiB = 1024 * 1024;
  char* w = (char*)d_ws;
  unsigned short* saB  = (unsigned short*)(w);                // 64 MiB
  unsigned short* stB  = (unsigned short*)(w + 64 * MiB);     // 64 MiB
  unsigned short* WqB  = (unsigned short*)(w + 128 * MiB);    // 2 MiB
  unsigned short* WkvB = (unsigned short*)(w + 130 * MiB);    // 4 MiB (Wk||Wv)
  unsigned short* WoB  = (unsigned short*)(w + 134 * MiB);    // 2 MiB
  unsigned short* Qb   = (unsigned short*)(w + 136 * MiB);    // 64 MiB -> 200
  // KV [M,2048] bf16 = 128 MiB -> d_out (dead before ln2 writes it).
  unsigned short* KVb = (unsigned short*)d_out;
  unsigned short* attb = Qb;   // in-place attention (row-local RAW, safe)
  unsigned short* oB   = stB;  // stB dead after KV-proj
  // saB stays live through ln2 (bf16 residual).

  const int nH8 = M * D / 8;   // 4,194,304
  const int nW8 = D * D / 8;   // 131,072
  // 1) all casts in one dispatch
  prep_kernel<<<(2 * nH8 + 4 * nW8) / 256, 256, 0, stream>>>(
      sa, st, Wq, Wk, Wv, Wo, saB, stB, WqB, WkvB, WoB, nH8, nW8);

  // 2) grouped Q-proj (512 blocks) + fused K/V-proj (1024 blocks)
  const int nbQ  = (M / 256) * (D / 256);        // 512
  const int nbKV = (M / 256) * (2 * D / 256);    // 1024
  gemm_qkv<<<nbQ + nbKV, 512, 0, stream>>>(
      saB, WqB, bq, Qb, D, nbQ,
      stB, WkvB, bk, bv, KVb, 2 * D, M, D);

  // 3) attention (in-place over Qb)
  attn_kernel<<<M / 4, 256, 0, stream>>>(Qb, KVb, attb);

  // 4) O-projection -> bf16 scratch (residual deferred to ln2)
  gemm_o<<<nbQ, 512, 0, stream>>>(attb, WoB, bo, oB, M, D, D);

  // 5) fused residual(bf16) + LayerNorm -> d_out
  ln2_kernel<<<M, 256, 0, stream>>>(oB, saB, out, lw, lb);
}

// Round 14
// 459.598 us; speedup vs baseline: 1.1571x; 1.0002x over previous
//
#include <hip/hip_runtime.h>

typedef unsigned int  uint32;
typedef float  f32x4   __attribute__((ext_vector_type(4)));
typedef __bf16 bf16x8  __attribute__((ext_vector_type(8)));
typedef short  s16x4   __attribute__((ext_vector_type(4)));

__device__ __forceinline__ float bf2f(unsigned int u) {
  return __builtin_bit_cast(float, u << 16);
}
__device__ __forceinline__ unsigned short f2bf(float f) {
  uint32 u = __builtin_bit_cast(uint32, f);
  u += 0x7fffu + ((u >> 16) & 1u);          // RNE
  return (unsigned short)(u >> 16);
}

__device__ __forceinline__ void gload_lds16(const void* g, void* l) {
  __builtin_amdgcn_global_load_lds(
      (const __attribute__((address_space(1))) void*)g,
      (__attribute__((address_space(3))) void*)l, 16, 0, 0);
}

// ---------------- merged fp32 -> bf16 casts (8 elems/thread) -------------
__device__ __forceinline__ void cast8(const float* __restrict__ x,
                                      unsigned short* __restrict__ y, int i) {
  const float4* xp = (const float4*)x;
  float4 a = xp[2 * i], b = xp[2 * i + 1];
  uint4 o;
  o.x = (uint32)f2bf(a.x) | ((uint32)f2bf(a.y) << 16);
  o.y = (uint32)f2bf(a.z) | ((uint32)f2bf(a.w) << 16);
  o.z = (uint32)f2bf(b.x) | ((uint32)f2bf(b.y) << 16);
  o.w = (uint32)f2bf(b.z) | ((uint32)f2bf(b.w) << 16);
  ((uint4*)y)[i] = o;
}

__global__ __launch_bounds__(256) void prep_kernel(
    const float* __restrict__ sa, const float* __restrict__ st,
    const float* __restrict__ Wq, const float* __restrict__ Wk,
    const float* __restrict__ Wv, const float* __restrict__ Wo,
    unsigned short* __restrict__ saB, unsigned short* __restrict__ stB,
    unsigned short* __restrict__ WqB, unsigned short* __restrict__ WkvB,
    unsigned short* __restrict__ WoB, int nH8, int nW8) {
  int i = blockIdx.x * 256 + threadIdx.x;       // block-uniform ranges
  if (i < nH8) { cast8(sa, saB, i); return; }
  i -= nH8;
  if (i < nH8) { cast8(st, stB, i); return; }
  i -= nH8;
  if (i < nW8) { cast8(Wq, WqB, i); return; }
  i -= nW8;
  if (i < nW8) { cast8(Wk, WkvB, i); return; }
  i -= nW8;
  if (i < nW8) { cast8(Wv, WkvB + (size_t)nW8 * 8, i); return; }
  i -= nW8;
  cast8(Wo, WoB, i);
}

// ------- bf16 GEMM body: C[M,N] = bf16(A[M,K] * W[N,K]^T + bias) -------
// Proven round-9/12 engine, verbatim.  (Round-13's 3-buffer variant was
// LDS-infeasible: 3 x (A32K+B32K) = 192KB > 160KB; reverted.)
// 256x256 tile, BK=64, 8 waves (2M x 4N), TWO LDS buffers (2 x 64KB),
// 2-tile-deep prefetch with counted vmcnt(8), raw s_barrier,
// st_16x32-style XOR swizzle (row 128B: chunk16 ^= row&7).
__device__ __forceinline__ void gemm_body(
    const unsigned short* __restrict__ A, const unsigned short* __restrict__ W,
    const float* __restrict__ bias, const float* __restrict__ bias2,
    unsigned short* __restrict__ Ob,
    int M, int N, int K, int nwg, int bid, char* smem) {
  const int tid  = threadIdx.x;
  const int lane = tid & 63;
  const int wave = tid >> 6;      // 0..7
  const int wr   = wave >> 2;     // 0..1 : m half (128 rows)
  const int wc   = wave & 3;      // 0..3 : n quarter (64 cols)

  // XCD chunk (bijective, nwg%8==0): n-fastest within chunk for A L2-reuse.
  const int xcd = bid & 7;
  const int r   = bid >> 3;                 // 0 .. nwg/8-1
  const int NT  = N >> 8;                   // n-tiles
  const int m0  = (xcd * ((nwg >> 3) / NT) + r / NT) << 8;
  const int n0  = (r % NT) << 8;

  f32x4 acc[8][4];
#pragma unroll
  for (int m = 0; m < 8; ++m)
#pragma unroll
    for (int n = 0; n < 4; ++n) acc[m][n] = (f32x4)0.0f;

  // ---- staging geometry (inverse-swizzled global source, linear LDS dest).
  const int pr8 = lane >> 3;
  const int cl  = (lane & 7) ^ pr8;
  const unsigned short* As = A + (size_t)(m0 + wave * 8 + pr8) * K + cl * 8;
  const unsigned short* Bs = W + (size_t)(n0 + wave * 8 + pr8) * K + cl * 8;
  const int dst = wave * 1024 + lane * 16;

#define STAGE(d, kt)                                                          \
  {                                                                           \
    char* sb = smem + (d) * 65536;                                            \
    const int ko = (kt) * 64;                                                 \
    _Pragma("unroll") for (int j = 0; j < 4; ++j)                             \
        gload_lds16(As + (size_t)(j * 64) * K + ko, sb + j * 8192 + dst);     \
    _Pragma("unroll") for (int j = 0; j < 4; ++j)                             \
        gload_lds16(Bs + (size_t)(j * 64) * K + ko,                           \
                    sb + 32768 + j * 8192 + dst);                             \
  }

  // ---- fragment read offsets (swizzled): row r, k-chunk c (= ks*4+kg):
  // byte = r*128 + ((c ^ (r&7))*16.
  const int fr = lane & 15, kg = lane >> 4;
  int cA[2];
#pragma unroll
  for (int ks = 0; ks < 2; ++ks)
    cA[ks] = fr * 128 + (((ks * 4 + kg) ^ (fr & 7)) * 16);
  const int abase = wr * 16384;           // + m*2048 + cA[ks]
  const int bbase = 32768 + wc * 8192;    // + n*2048 + cA[ks]

#define PH_AB(base_, av_, bv_, mlo, ks)                                       \
  {                                                                           \
    _Pragma("unroll") for (int m = 0; m < 4; ++m)                             \
        av_[m] = *(const bf16x8*)((base_) + abase + ((mlo) + m) * 2048 +      \
                                  cA[ks]);                                    \
    _Pragma("unroll") for (int n = 0; n < 4; ++n)                             \
        bv_[n] = *(const bf16x8*)((base_) + bbase + n * 2048 + cA[ks]);       \
  }
#define PH_A(base_, av_, mlo, ks)                                             \
  {                                                                           \
    _Pragma("unroll") for (int m = 0; m < 4; ++m)                             \
        av_[m] = *(const bf16x8*)((base_) + abase + ((mlo) + m) * 2048 +      \
                                  cA[ks]);                                    \
  }
#define PH_MFMA(av_, bv_, mlo)                                                \
  __builtin_amdgcn_s_setprio(1);                                              \
  _Pragma("unroll") for (int m = 0; m < 4; ++m)                               \
      _Pragma("unroll") for (int n = 0; n < 4; ++n)                           \
          acc[(mlo) + m][n] = __builtin_amdgcn_mfma_f32_16x16x32_bf16(        \
              av_[m], bv_[n], acc[(mlo) + m][n], 0, 0, 0);                    \
  __builtin_amdgcn_s_setprio(0);

  const int nt = K >> 6;  // 64-wide K-tiles
  STAGE(0, 0);
  STAGE(1, 1);

  for (int t = 0; t < nt - 2; ++t) {
    // in flight: t (8) + t+1 (8).  Drain to 8 -> tile t landed.
    asm volatile("s_waitcnt vmcnt(8)" ::: "memory");
    __builtin_amdgcn_s_barrier();
    const char* base = smem + (t & 1) * 65536;
    bf16x8 a0[4], a1[4], b0[4], b1[4];
    PH_AB(base, a0, b0, 0, 0);
    PH_MFMA(a0, b0, 0);
    PH_A(base, a1, 4, 0);
    PH_MFMA(a1, b0, 4);
    PH_AB(base, a0, b1, 0, 1);
    PH_MFMA(a0, b1, 0);
    PH_A(base, a1, 4, 1);
    asm volatile("s_waitcnt lgkmcnt(0)" ::: "memory");
    __builtin_amdgcn_s_barrier();          // all waves done reading buf
    STAGE(t & 1, t + 2);                   // overwrite with tile t+2
    __builtin_amdgcn_sched_barrier(0);
    PH_MFMA(a1, b1, 4);
  }
  // tail: tiles nt-2 (vmcnt 8) and nt-1 (vmcnt 0), no staging
#pragma unroll
  for (int tt = 0; tt < 2; ++tt) {
    if (tt == 0)
      asm volatile("s_waitcnt vmcnt(8)" ::: "memory");
    else
      asm volatile("s_waitcnt vmcnt(0)" ::: "memory");
    __builtin_amdgcn_s_barrier();
    const char* base = smem + ((nt - 2 + tt) & 1) * 65536;
    bf16x8 a0[4], a1[4], b0[4], b1[4];
    PH_AB(base, a0, b0, 0, 0);
    PH_MFMA(a0, b0, 0);
    PH_A(base, a1, 4, 0);
    PH_MFMA(a1, b0, 4);
    PH_AB(base, a0, b1, 0, 1);
    PH_MFMA(a0, b1, 0);
    PH_A(base, a1, 4, 1);
    PH_MFMA(a1, b1, 4);
  }

  // ---- epilogue: C/D map col = lane&15, row = (lane>>4)*4 + i.
  // Row-major store order so each row's 4 chunks issue back-to-back.
  // Split bias (fused KV problem): block-uniform n0 decides bk vs bv.
  const float* bsel = (bias2 != nullptr && n0 >= 1024) ? (bias2 - 1024) : bias;
  const int r4 = (lane >> 4) * 4;
  float bvv[4];
#pragma unroll
  for (int n = 0; n < 4; ++n) bvv[n] = bsel[n0 + wc * 64 + n * 16 + fr];
#pragma unroll
  for (int m = 0; m < 8; ++m) {
    const int rowb = m0 + wr * 128 + m * 16 + r4;
#pragma unroll
    for (int i = 0; i < 4; ++i) {
      const size_t rb = (size_t)(rowb + i) * N;
#pragma unroll
      for (int n = 0; n < 4; ++n) {
        const size_t idx = rb + (n0 + wc * 64 + n * 16 + fr);
        Ob[idx] = f2bf(acc[m][n][i] + bvv[n]);
      }
    }
  }
#undef STAGE
#undef PH_AB
#undef PH_A
#undef PH_MFMA
}

// ---- grouped Q-proj + KV-proj in one dispatch (blocks [0,nb0) -> Q) ----
__global__ __launch_bounds__(512, 2) void gemm_qkv(
    const unsigned short* A0, const unsigned short* W0, const float* b0,
    unsigned short* C0, int N0, int nb0,
    const unsigned short* A1, const unsigned short* W1, const float* b1lo,
    const float* b1hi, unsigned short* C1, int N1, int M, int K) {
  __shared__ char smem[131072];  // 2 bufs x (A 32KB | B 32KB)
  if ((int)blockIdx.x < nb0)
    gemm_body(A0, W0, b0, nullptr, C0, M, N0, K, nb0, blockIdx.x, smem);
  else
    gemm_body(A1, W1, b1lo, b1hi, C1, M, N1, K, gridDim.x - nb0,
              blockIdx.x - nb0, smem);
}

// ---- O-projection: bf16 out (residual fused into ln2) ----
__global__ __launch_bounds__(512, 2) void gemm_o(
    const unsigned short* A, const unsigned short* W, const float* bias,
    unsigned short* C, int M, int N, int K) {
  __shared__ char smem[131072];
  gemm_body(A, W, bias, nullptr, C, M, N, K, gridDim.x, blockIdx.x, smem);
}

// ---------------- head-wise attention, MFMA, one wave per row b ----------
// Q: [B,1024].  K,V packed in KV [B,2048]: K at +0, V at +1024.
// Out: [B,1024] with idx = d*16 + h.  O may ALIAS Q (in-place): each wave
// fully loads its row's Q into registers before any store.
__global__ __launch_bounds__(256) void attn_kernel(
    const unsigned short* __restrict__ Q, const unsigned short* __restrict__ KV,
    unsigned short* __restrict__ O) {
  const int tid  = threadIdx.x;
  const int lane = tid & 63;
  const int wave = tid >> 6;
  const int b    = blockIdx.x * 4 + wave;
  const size_t qb  = (size_t)b * 1024;
  const size_t kvb = (size_t)b * 2048;
  const int fr = lane & 15, kg = lane >> 4;

  // ---- QK^T (transposed): A = K rows (g), B = Q rows (h), K-dim = d (64).
  const bf16x8 kf0 = *(const bf16x8*)(KV + kvb + fr * 64 + kg * 8);
  const bf16x8 kf1 = *(const bf16x8*)(KV + kvb + fr * 64 + 32 + kg * 8);
  const bf16x8 qf0 = *(const bf16x8*)(Q + qb + fr * 64 + kg * 8);
  const bf16x8 qf1 = *(const bf16x8*)(Q + qb + fr * 64 + 32 + kg * 8);

  // ---- V B-fragments: lane (fr=d_local, kg) holds V[kg*4+j][c*16+fr].
  s16x4 vb[4];
#pragma unroll
  for (int c = 0; c < 4; ++c) {
    const unsigned short* vp = KV + kvb + 1024 + c * 16 + fr + kg * 4 * 64;
    s16x4 t;
    t[0] = (short)vp[0];
    t[1] = (short)vp[64];
    t[2] = (short)vp[128];
    t[3] = (short)vp[192];
    vb[c] = t;
  }

  f32x4 es = (f32x4)0.0f;
  es = __builtin_amdgcn_mfma_f32_16x16x32_bf16(kf0, qf0, es, 0, 0, 0);
  es = __builtin_amdgcn_mfma_f32_16x16x32_bf16(kf1, qf1, es, 0, 0, 0);

  // ---- softmax over g (rows): in-lane 4 + lanes L^16, L^32.
  float s0 = es[0] * 0.125f, s1 = es[1] * 0.125f;
  float s2 = es[2] * 0.125f, s3 = es[3] * 0.125f;
  float mx = fmaxf(fmaxf(s0, s1), fmaxf(s2, s3));
  mx = fmaxf(mx, __shfl_xor(mx, 16, 64));
  mx = fmaxf(mx, __shfl_xor(mx, 32, 64));
  float e0 = __expf(s0 - mx), e1 = __expf(s1 - mx);
  float e2 = __expf(s2 - mx), e3 = __expf(s3 - mx);
  float sum = e0 + e1 + e2 + e3;
  sum += __shfl_xor(sum, 16, 64);
  sum += __shfl_xor(sum, 32, 64);
  const float inv = 1.0f / sum;

  s16x4 pa;
  pa[0] = (short)f2bf(e0 * inv);
  pa[1] = (short)f2bf(e1 * inv);
  pa[2] = (short)f2bf(e2 * inv);
  pa[3] = (short)f2bf(e3 * inv);

  // ---- PV: out[h, c*16+d'] via 4x mfma 16x16x16 (K = g = 16).
  unsigned short* Ob = O + qb;
#pragma unroll
  for (int c = 0; c < 4; ++c) {
    f32x4 o = __builtin_amdgcn_mfma_f32_16x16x16bf16_1k(pa, vb[c],
                                                        (f32x4)0.0f, 0, 0, 0);
    uint2 st;
    st.x = (uint32)f2bf(o[0]) | ((uint32)f2bf(o[1]) << 16);
    st.y = (uint32)f2bf(o[2]) | ((uint32)f2bf(o[3]) << 16);
    *(uint2*)(Ob + c * 256 + fr * 16 + kg * 4) = st;
  }
}

// --- fused residual + LayerNorm: Y = LN(bf16(oproj) + bf16(sa)) ---
__global__ __launch_bounds__(256) void ln2_kernel(
    const unsigned short* __restrict__ Ob,
    const unsigned short* __restrict__ saB, float* __restrict__ Y,
    const float* __restrict__ gw, const float* __restrict__ gb) {
  const size_t rb = (size_t)blockIdx.x * 1024;
  const int tid = threadIdx.x;
  const uint2 ov = ((const uint2*)(Ob + rb))[tid];          // 4 bf16
  const uint2 sv = ((const uint2*)(saB + rb))[tid];         // 4 bf16
  float4 v;
  v.x = bf2f(ov.x & 0xffff) + bf2f(sv.x & 0xffff);
  v.y = bf2f(ov.x >> 16)    + bf2f(sv.x >> 16);
  v.z = bf2f(ov.y & 0xffff) + bf2f(sv.y & 0xffff);
  v.w = bf2f(ov.y >> 16)    + bf2f(sv.y >> 16);
  float s  = v.x + v.y + v.z + v.w;
  float s2 = v.x * v.x + v.y * v.y + v.z * v.z + v.w * v.w;
#pragma unroll
  for (int o = 32; o > 0; o >>= 1) {
    s  += __shfl_xor(s, o, 64);
    s2 += __shfl_xor(s2, o, 64);
  }
  __shared__ float rs[4], rq[4];
  const int wave = tid >> 6;
  if ((tid & 63) == 0) { rs[wave] = s; rq[wave] = s2; }
  __syncthreads();
  s  = rs[0] + rs[1] + rs[2] + rs[3];
  s2 = rq[0] + rq[1] + rq[2] + rq[3];
  const float mean = s * (1.f / 1024.f);
  const float var  = s2 * (1.f / 1024.f) - mean * mean;
  const float r = rsqrtf(var + 1e-5f);
  const float4 w = ((const float4*)gw)[tid];
  const float4 bb = ((const float4*)gb)[tid];
  float4 o;
  o.x = (v.x - mean) * r * w.x + bb.x;
  o.y = (v.y - mean) * r * w.y + bb.y;
  o.z = (v.z - mean) * r * w.z + bb.z;
  o.w = (v.w - mean) * r * w.w + bb.w;
  ((float4*)(Y + rb))[tid] = o;
}

extern "C" void kernel_launch(void* const* d_in, const int* in_sizes, int n_in,
                              void* d_out, int out_size, void* d_ws,
                              size_t ws_size, hipStream_t stream) {
  const float* sa = (const float*)d_in[0];
  const float* st = (const float*)d_in[1];
  const float* Wq = (const float*)d_in[2];
  const float* bq = (const float*)d_in[3];
  const float* Wk = (const float*)d_in[4];
  const float* bk = (const float*)d_in[5];
  const float* Wv = (const float*)d_in[6];
  const float* bv = (const float*)d_in[7];
  const float* Wo = (const float*)d_in[8];
  const float* bo = (const float*)d_in[9];
  const float* lw = (const float*)d_in[10];
  const float* lb = (const float*)d_in[11];
  float* out = (float*)d_out;

  const int M = 32768, D = 1024;
  const size_t MiB = 1024 * 1024;
  char* w = (char*)d_ws;
  unsigned short* saB  = (unsigned short*)(w);                // 64 MiB
  unsigned short* stB  = (unsigned short*)(w + 64 * MiB);     // 64 MiB
  unsigned short* WqB  = (unsigned short*)(w + 128 * MiB);    // 2 MiB
  unsigned short* WkvB = (unsigned short*)(w + 130 * MiB);    // 4 MiB (Wk||Wv)
  unsigned short* WoB  = (unsigned short*)(w + 134 * MiB);    // 2 MiB
  unsigned short* Qb   = (unsigned short*)(w + 136 * MiB);    // 64 MiB -> 200
  // KV [M,2048] bf16 = 128 MiB -> d_out (dead before ln2 writes it).
  unsigned short* KVb = (unsigned short*)d_out;
  unsigned short* attb = Qb;   // in-place attention (row-local RAW, safe)
  unsigned short* oB   = stB;  // stB dead after KV-proj
  // saB stays live through ln2 (bf16 residual).

  const int nH8 = M * D / 8;   // 4,194,304
  const int nW8 = D * D / 8;   // 131,072
  // 1) all casts in one dispatch
  prep_kernel<<<(2 * nH8 + 4 * nW8) / 256, 256, 0, stream>>>(
      sa, st, Wq, Wk, Wv, Wo, saB, stB, WqB, WkvB, WoB, nH8, nW8);

  // 2) grouped Q-proj (512 blocks) + fused K/V-proj (1024 blocks)
  const int nbQ  = (M / 256) * (D / 256);        // 512
  const int nbKV = (M / 256) * (2 * D / 256);    // 1024
  gemm_qkv<<<nbQ + nbKV, 512, 0, stream>>>(
      saB, WqB, bq, Qb, D, nbQ,
      stB, WkvB, bk, bv, KVb, 2 * D, M, D);

  // 3) attention (in-place over Qb)
  attn_kernel<<<M / 4, 256, 0, stream>>>(Qb, KVb, attb);

  // 4) O-projection -> bf16 scratch (residual deferred to ln2)
  gemm_o<<<nbQ, 512, 0, stream>>>(attb, WoB, bo, oB, M, D, D);

  // 5) fused residual(bf16) + LayerNorm -> d_out
  ln2_kernel<<<M, 256, 0, stream>>>(oB, saB, out, lw, lb);
}

// Round 15
// 449.066 us; speedup vs baseline: 1.1843x; 1.0235x over previous
//
#include <hip/hip_runtime.h>

typedef unsigned int  uint32;
typedef float  f32x4   __attribute__((ext_vector_type(4)));
typedef __bf16 bf16x8  __attribute__((ext_vector_type(8)));
typedef short  s16x4   __attribute__((ext_vector_type(4)));

__device__ __forceinline__ float bf2f(unsigned int u) {
  return __builtin_bit_cast(float, u << 16);
}
__device__ __forceinline__ unsigned short f2bf(float f) {
  uint32 u = __builtin_bit_cast(uint32, f);
  u += 0x7fffu + ((u >> 16) & 1u);          // RNE
  return (unsigned short)(u >> 16);
}

__device__ __forceinline__ void gload_lds16(const void* g, void* l) {
  __builtin_amdgcn_global_load_lds(
      (const __attribute__((address_space(1))) void*)g,
      (__attribute__((address_space(3))) void*)l, 16, 0, 0);
}

// ---------------- merged fp32 -> bf16 casts (8 elems/thread) -------------
__device__ __forceinline__ void cast8(const float* __restrict__ x,
                                      unsigned short* __restrict__ y, int i) {
  const float4* xp = (const float4*)x;
  float4 a = xp[2 * i], b = xp[2 * i + 1];
  uint4 o;
  o.x = (uint32)f2bf(a.x) | ((uint32)f2bf(a.y) << 16);
  o.y = (uint32)f2bf(a.z) | ((uint32)f2bf(a.w) << 16);
  o.z = (uint32)f2bf(b.x) | ((uint32)f2bf(b.y) << 16);
  o.w = (uint32)f2bf(b.z) | ((uint32)f2bf(b.w) << 16);
  ((uint4*)y)[i] = o;
}

__global__ __launch_bounds__(256) void prep_kernel(
    const float* __restrict__ sa, const float* __restrict__ st,
    const float* __restrict__ Wq, const float* __restrict__ Wk,
    const float* __restrict__ Wv, const float* __restrict__ Wo,
    unsigned short* __restrict__ saB, unsigned short* __restrict__ stB,
    unsigned short* __restrict__ WqB, unsigned short* __restrict__ WkvB,
    unsigned short* __restrict__ WoB, int nH8, int nW8) {
  int i = blockIdx.x * 256 + threadIdx.x;       // block-uniform ranges
  if (i < nH8) { cast8(sa, saB, i); return; }
  i -= nH8;
  if (i < nH8) { cast8(st, stB, i); return; }
  i -= nH8;
  if (i < nW8) { cast8(Wq, WqB, i); return; }
  i -= nW8;
  if (i < nW8) { cast8(Wk, WkvB, i); return; }
  i -= nW8;
  if (i < nW8) { cast8(Wv, WkvB + (size_t)nW8 * 8, i); return; }
  i -= nW8;
  cast8(Wo, WoB, i);
}

// ------- bf16 GEMM body: C[M,N] = bf16(A[M,K] * W[N,K]^T + bias) -------
// Round-14 engine with the guide's verified "minimum 2-phase" K-loop:
//   per tile: STAGE(next) at TOP -> quadrant ds_read/MFMA body (compiler
//   data-dep lgkm waits) -> vmcnt(0) + ONE barrier (publish + release).
// RAW: tile t staged in iter t-1, drained by its end vmcnt(0)+barrier.
// WAR: all reads of buf^1 are consumed (lgkm-waited) before the barrier
// that precedes iter t's overwrite of it.
// 256x256 tile, BK=64, 8 waves (2M x 4N), TWO LDS buffers (2 x 64KB),
// st_16x32-style XOR swizzle (row 128B: chunk16 ^= row&7).
__device__ __forceinline__ void gemm_body(
    const unsigned short* __restrict__ A, const unsigned short* __restrict__ W,
    const float* __restrict__ bias, const float* __restrict__ bias2,
    unsigned short* __restrict__ Ob,
    int M, int N, int K, int nwg, int bid, char* smem) {
  const int tid  = threadIdx.x;
  const int lane = tid & 63;
  const int wave = tid >> 6;      // 0..7
  const int wr   = wave >> 2;     // 0..1 : m half (128 rows)
  const int wc   = wave & 3;      // 0..3 : n quarter (64 cols)

  // XCD chunk (bijective, nwg%8==0): n-fastest within chunk for A L2-reuse.
  const int xcd = bid & 7;
  const int r   = bid >> 3;                 // 0 .. nwg/8-1
  const int NT  = N >> 8;                   // n-tiles
  const int m0  = (xcd * ((nwg >> 3) / NT) + r / NT) << 8;
  const int n0  = (r % NT) << 8;

  f32x4 acc[8][4];
#pragma unroll
  for (int m = 0; m < 8; ++m)
#pragma unroll
    for (int n = 0; n < 4; ++n) acc[m][n] = (f32x4)0.0f;

  // ---- staging geometry (inverse-swizzled global source, linear LDS dest).
  const int pr8 = lane >> 3;
  const int cl  = (lane & 7) ^ pr8;
  const unsigned short* As = A + (size_t)(m0 + wave * 8 + pr8) * K + cl * 8;
  const unsigned short* Bs = W + (size_t)(n0 + wave * 8 + pr8) * K + cl * 8;
  const int dst = wave * 1024 + lane * 16;

#define STAGE(d, kt)                                                          \
  {                                                                           \
    char* sb = smem + (d) * 65536;                                            \
    const int ko = (kt) * 64;                                                 \
    _Pragma("unroll") for (int j = 0; j < 4; ++j)                             \
        gload_lds16(As + (size_t)(j * 64) * K + ko, sb + j * 8192 + dst);     \
    _Pragma("unroll") for (int j = 0; j < 4; ++j)                             \
        gload_lds16(Bs + (size_t)(j * 64) * K + ko,                           \
                    sb + 32768 + j * 8192 + dst);                             \
  }

  // ---- fragment read offsets (swizzled): row r, k-chunk c (= ks*4+kg):
  // byte = r*128 + ((c ^ (r&7))*16.
  const int fr = lane & 15, kg = lane >> 4;
  int cA[2];
#pragma unroll
  for (int ks = 0; ks < 2; ++ks)
    cA[ks] = fr * 128 + (((ks * 4 + kg) ^ (fr & 7)) * 16);
  const int abase = wr * 16384;           // + m*2048 + cA[ks]
  const int bbase = 32768 + wc * 8192;    // + n*2048 + cA[ks]

#define PH_AB(base_, av_, bv_, mlo, ks)                                       \
  {                                                                           \
    _Pragma("unroll") for (int m = 0; m < 4; ++m)                             \
        av_[m] = *(const bf16x8*)((base_) + abase + ((mlo) + m) * 2048 +      \
                                  cA[ks]);                                    \
    _Pragma("unroll") for (int n = 0; n < 4; ++n)                             \
        bv_[n] = *(const bf16x8*)((base_) + bbase + n * 2048 + cA[ks]);       \
  }
#define PH_A(base_, av_, mlo, ks)                                             \
  {                                                                           \
    _Pragma("unroll") for (int m = 0; m < 4; ++m)                             \
        av_[m] = *(const bf16x8*)((base_) + abase + ((mlo) + m) * 2048 +      \
                                  cA[ks]);                                    \
  }
#define PH_MFMA(av_, bv_, mlo)                                                \
  __builtin_amdgcn_s_setprio(1);                                              \
  _Pragma("unroll") for (int m = 0; m < 4; ++m)                               \
      _Pragma("unroll") for (int n = 0; n < 4; ++n)                           \
          acc[(mlo) + m][n] = __builtin_amdgcn_mfma_f32_16x16x32_bf16(        \
              av_[m], bv_[n], acc[(mlo) + m][n], 0, 0, 0);                    \
  __builtin_amdgcn_s_setprio(0);

  const int nt = K >> 6;  // 64-wide K-tiles
  // prologue: stage tile 0, drain, publish.
  STAGE(0, 0);
  asm volatile("s_waitcnt vmcnt(0)" ::: "memory");
  __builtin_amdgcn_s_barrier();

  for (int t = 0; t < nt; ++t) {
    const int cur = t & 1;
    // issue next-tile loads FIRST: they get the whole body to land.
    if (t + 1 < nt) STAGE(cur ^ 1, t + 1);
    const char* base = smem + cur * 65536;
    bf16x8 a0[4], a1[4], b0[4], b1[4];
    PH_AB(base, a0, b0, 0, 0);
    PH_MFMA(a0, b0, 0);
    PH_A(base, a1, 4, 0);
    PH_MFMA(a1, b0, 4);
    PH_AB(base, a0, b1, 0, 1);
    PH_MFMA(a0, b1, 0);
    PH_A(base, a1, 4, 1);
    PH_MFMA(a1, b1, 4);
    // single sync point: tile t+1 landed (RAW) AND all waves' reads of
    // buf cur consumed (WAR) -> next iter may read cur^1 / overwrite cur.
    asm volatile("s_waitcnt vmcnt(0)" ::: "memory");
    __builtin_amdgcn_s_barrier();
  }

  // ---- epilogue: C/D map col = lane&15, row = (lane>>4)*4 + i.
  // Row-major store order so each row's 4 chunks issue back-to-back.
  // Split bias (fused KV problem): block-uniform n0 decides bk vs bv.
  const float* bsel = (bias2 != nullptr && n0 >= 1024) ? (bias2 - 1024) : bias;
  const int r4 = (lane >> 4) * 4;
  float bvv[4];
#pragma unroll
  for (int n = 0; n < 4; ++n) bvv[n] = bsel[n0 + wc * 64 + n * 16 + fr];
#pragma unroll
  for (int m = 0; m < 8; ++m) {
    const int rowb = m0 + wr * 128 + m * 16 + r4;
#pragma unroll
    for (int i = 0; i < 4; ++i) {
      const size_t rb = (size_t)(rowb + i) * N;
#pragma unroll
      for (int n = 0; n < 4; ++n) {
        const size_t idx = rb + (n0 + wc * 64 + n * 16 + fr);
        Ob[idx] = f2bf(acc[m][n][i] + bvv[n]);
      }
    }
  }
#undef STAGE
#undef PH_AB
#undef PH_A
#undef PH_MFMA
}

// ---- grouped Q-proj + KV-proj in one dispatch (blocks [0,nb0) -> Q) ----
__global__ __launch_bounds__(512, 2) void gemm_qkv(
    const unsigned short* A0, const unsigned short* W0, const float* b0,
    unsigned short* C0, int N0, int nb0,
    const unsigned short* A1, const unsigned short* W1, const float* b1lo,
    const float* b1hi, unsigned short* C1, int N1, int M, int K) {
  __shared__ char smem[131072];  // 2 bufs x (A 32KB | B 32KB)
  if ((int)blockIdx.x < nb0)
    gemm_body(A0, W0, b0, nullptr, C0, M, N0, K, nb0, blockIdx.x, smem);
  else
    gemm_body(A1, W1, b1lo, b1hi, C1, M, N1, K, gridDim.x - nb0,
              blockIdx.x - nb0, smem);
}

// ---- O-projection: bf16 out (residual fused into ln2) ----
__global__ __launch_bounds__(512, 2) void gemm_o(
    const unsigned short* A, const unsigned short* W, const float* bias,
    unsigned short* C, int M, int N, int K) {
  __shared__ char smem[131072];
  gemm_body(A, W, bias, nullptr, C, M, N, K, gridDim.x, blockIdx.x, smem);
}

// ---------------- head-wise attention, MFMA, one wave per row b ----------
// Q: [B,1024].  K,V packed in KV [B,2048]: K at +0, V at +1024.
// Out: [B,1024] with idx = d*16 + h.  O may ALIAS Q (in-place): each wave
// fully loads its row's Q into registers before any store.
__global__ __launch_bounds__(256) void attn_kernel(
    const unsigned short* __restrict__ Q, const unsigned short* __restrict__ KV,
    unsigned short* __restrict__ O) {
  const int tid  = threadIdx.x;
  const int lane = tid & 63;
  const int wave = tid >> 6;
  const int b    = blockIdx.x * 4 + wave;
  const size_t qb  = (size_t)b * 1024;
  const size_t kvb = (size_t)b * 2048;
  const int fr = lane & 15, kg = lane >> 4;

  // ---- QK^T (transposed): A = K rows (g), B = Q rows (h), K-dim = d (64).
  const bf16x8 kf0 = *(const bf16x8*)(KV + kvb + fr * 64 + kg * 8);
  const bf16x8 kf1 = *(const bf16x8*)(KV + kvb + fr * 64 + 32 + kg * 8);
  const bf16x8 qf0 = *(const bf16x8*)(Q + qb + fr * 64 + kg * 8);
  const bf16x8 qf1 = *(const bf16x8*)(Q + qb + fr * 64 + 32 + kg * 8);

  // ---- V B-fragments: lane (fr=d_local, kg) holds V[kg*4+j][c*16+fr].
  s16x4 vb[4];
#pragma unroll
  for (int c = 0; c < 4; ++c) {
    const unsigned short* vp = KV + kvb + 1024 + c * 16 + fr + kg * 4 * 64;
    s16x4 t;
    t[0] = (short)vp[0];
    t[1] = (short)vp[64];
    t[2] = (short)vp[128];
    t[3] = (short)vp[192];
    vb[c] = t;
  }

  f32x4 es = (f32x4)0.0f;
  es = __builtin_amdgcn_mfma_f32_16x16x32_bf16(kf0, qf0, es, 0, 0, 0);
  es = __builtin_amdgcn_mfma_f32_16x16x32_bf16(kf1, qf1, es, 0, 0, 0);

  // ---- softmax over g (rows): in-lane 4 + lanes L^16, L^32.
  float s0 = es[0] * 0.125f, s1 = es[1] * 0.125f;
  float s2 = es[2] * 0.125f, s3 = es[3] * 0.125f;
  float mx = fmaxf(fmaxf(s0, s1), fmaxf(s2, s3));
  mx = fmaxf(mx, __shfl_xor(mx, 16, 64));
  mx = fmaxf(mx, __shfl_xor(mx, 32, 64));
  float e0 = __expf(s0 - mx), e1 = __expf(s1 - mx);
  float e2 = __expf(s2 - mx), e3 = __expf(s3 - mx);
  float sum = e0 + e1 + e2 + e3;
  sum += __shfl_xor(sum, 16, 64);
  sum += __shfl_xor(sum, 32, 64);
  const float inv = 1.0f / sum;

  s16x4 pa;
  pa[0] = (short)f2bf(e0 * inv);
  pa[1] = (short)f2bf(e1 * inv);
  pa[2] = (short)f2bf(e2 * inv);
  pa[3] = (short)f2bf(e3 * inv);

  // ---- PV: out[h, c*16+d'] via 4x mfma 16x16x16 (K = g = 16).
  unsigned short* Ob = O + qb;
#pragma unroll
  for (int c = 0; c < 4; ++c) {
    f32x4 o = __builtin_amdgcn_mfma_f32_16x16x16bf16_1k(pa, vb[c],
                                                        (f32x4)0.0f, 0, 0, 0);
    uint2 st;
    st.x = (uint32)f2bf(o[0]) | ((uint32)f2bf(o[1]) << 16);
    st.y = (uint32)f2bf(o[2]) | ((uint32)f2bf(o[3]) << 16);
    *(uint2*)(Ob + c * 256 + fr * 16 + kg * 4) = st;
  }
}

// --- fused residual + LayerNorm: Y = LN(bf16(oproj) + bf16(sa)) ---
__global__ __launch_bounds__(256) void ln2_kernel(
    const unsigned short* __restrict__ Ob,
    const unsigned short* __restrict__ saB, float* __restrict__ Y,
    const float* __restrict__ gw, const float* __restrict__ gb) {
  const size_t rb = (size_t)blockIdx.x * 1024;
  const int tid = threadIdx.x;
  const uint2 ov = ((const uint2*)(Ob + rb))[tid];          // 4 bf16
  const uint2 sv = ((const uint2*)(saB + rb))[tid];         // 4 bf16
  float4 v;
  v.x = bf2f(ov.x & 0xffff) + bf2f(sv.x & 0xffff);
  v.y = bf2f(ov.x >> 16)    + bf2f(sv.x >> 16);
  v.z = bf2f(ov.y & 0xffff) + bf2f(sv.y & 0xffff);
  v.w = bf2f(ov.y >> 16)    + bf2f(sv.y >> 16);
  float s  = v.x + v.y + v.z + v.w;
  float s2 = v.x * v.x + v.y * v.y + v.z * v.z + v.w * v.w;
#pragma unroll
  for (int o = 32; o > 0; o >>= 1) {
    s  += __shfl_xor(s, o, 64);
    s2 += __shfl_xor(s2, o, 64);
  }
  __shared__ float rs[4], rq[4];
  const int wave = tid >> 6;
  if ((tid & 63) == 0) { rs[wave] = s; rq[wave] = s2; }
  __syncthreads();
  s  = rs[0] + rs[1] + rs[2] + rs[3];
  s2 = rq[0] + rq[1] + rq[2] + rq[3];
  const float mean = s * (1.f / 1024.f);
  const float var  = s2 * (1.f / 1024.f) - mean * mean;
  const float r = rsqrtf(var + 1e-5f);
  const float4 w = ((const float4*)gw)[tid];
  const float4 bb = ((const float4*)gb)[tid];
  float4 o;
  o.x = (v.x - mean) * r * w.x + bb.x;
  o.y = (v.y - mean) * r * w.y + bb.y;
  o.z = (v.z - mean) * r * w.z + bb.z;
  o.w = (v.w - mean) * r * w.w + bb.w;
  ((float4*)(Y + rb))[tid] = o;
}

extern "C" void kernel_launch(void* const* d_in, const int* in_sizes, int n_in,
                              void* d_out, int out_size, void* d_ws,
                              size_t ws_size, hipStream_t stream) {
  const float* sa = (const float*)d_in[0];
  const float* st = (const float*)d_in[1];
  const float* Wq = (const float*)d_in[2];
  const float* bq = (const float*)d_in[3];
  const float* Wk = (const float*)d_in[4];
  const float* bk = (const float*)d_in[5];
  const float* Wv = (const float*)d_in[6];
  const float* bv = (const float*)d_in[7];
  const float* Wo = (const float*)d_in[8];
  const float* bo = (const float*)d_in[9];
  const float* lw = (const float*)d_in[10];
  const float* lb = (const float*)d_in[11];
  float* out = (float*)d_out;

  const int M = 32768, D = 1024;
  const size_t MiB = 1024 * 1024;
  char* w = (char*)d_ws;
  unsigned short* saB  = (unsigned short*)(w);                // 64 MiB
  unsigned short* stB  = (unsigned short*)(w + 64 * MiB);     // 64 MiB
  unsigned short* WqB  = (unsigned short*)(w + 128 * MiB);    // 2 MiB
  unsigned short* WkvB = (unsigned short*)(w + 130 * MiB);    // 4 MiB (Wk||Wv)
  unsigned short* WoB  = (unsigned short*)(w + 134 * MiB);    // 2 MiB
  unsigned short* Qb   = (unsigned short*)(w + 136 * MiB);    // 64 MiB -> 200
  // KV [M,2048] bf16 = 128 MiB -> d_out (dead before ln2 writes it).
  unsigned short* KVb = (unsigned short*)d_out;
  unsigned short* attb = Qb;   // in-place attention (row-local RAW, safe)
  unsigned short* oB   = stB;  // stB dead after KV-proj
  // saB stays live through ln2 (bf16 residual).

  const int nH8 = M * D / 8;   // 4,194,304
  const int nW8 = D * D / 8;   // 131,072
  // 1) all casts in one dispatch
  prep_kernel<<<(2 * nH8 + 4 * nW8) / 256, 256, 0, stream>>>(
      sa, st, Wq, Wk, Wv, Wo, saB, stB, WqB, WkvB, WoB, nH8, nW8);

  // 2) grouped Q-proj (512 blocks) + fused K/V-proj (1024 blocks)
  const int nbQ  = (M / 256) * (D / 256);        // 512
  const int nbKV = (M / 256) * (2 * D / 256);    // 1024
  gemm_qkv<<<nbQ + nbKV, 512, 0, stream>>>(
      saB, WqB, bq, Qb, D, nbQ,
      stB, WkvB, bk, bv, KVb, 2 * D, M, D);

  // 3) attention (in-place over Qb)
  attn_kernel<<<M / 4, 256, 0, stream>>>(Qb, KVb, attb);

  // 4) O-projection -> bf16 scratch (residual deferred to ln2)
  gemm_o<<<nbQ, 512, 0, stream>>>(attb, WoB, bo, oB, M, D, D);

  // 5) fused residual(bf16) + LayerNorm -> d_out
  ln2_kernel<<<M, 256, 0, stream>>>(oB, saB, out, lw, lb);
}